// Round 4
// baseline (471.206 us; speedup 1.0000x reference)
//
#include <hip/hip_runtime.h>
#include <stdint.h>

// GCN: 3-layer GraphConv (norm='right'), N=50000 nodes, E=600000 edges,
// dims 128 -> 128 -> 128 -> 64.
//
//   build CSR by dst (deg count -> hierarchical scan -> bucket fill)
//   prep: W1,W2,W3 -> transposed split-bf16 (hi+lo) [reuses cursor buffer]
//   L1: agg128(features)->B0 ; mfma_gemm128(B0,Wt1,b1,relu)->B1
//   L2: agg128(B1)->B0       ; mfma_gemm128(B0,Wt2,b2,relu)->B1
//   L3: mfma_gemm64(B1,Wt3)->B0(T) ; agg64(T)+b3 -> d_out
//
// R1: hierarchical scan (scan_k 110us -> ~5us).                 [442us total]
// R3: GEMMs moved to MFMA split-bf16 (a=ah+al, 3x mfma_16x16x32_bf16,
//     fp32-class accuracy). No LDS/barriers in gemm; W pre-transposed+split.
//     Frag layout: A/B lane l elem j: k=(j>>2)*16+4*(l>>4)+(j&3), row/col=l&15;
//     C/D: col=lane&15, row=4*(lane>>4)+reg (guide m89/m156-verified).

#define N_NODES 50000
#define N_EDGES 600000
#define SCAN_CHUNK 1024

typedef __attribute__((ext_vector_type(8))) short short8v;
typedef __attribute__((ext_vector_type(4))) short short4v;
typedef __attribute__((ext_vector_type(4))) float f32x4;

// ---------------- CSR build ----------------

__global__ void count_deg_k(const int* __restrict__ dst, int* __restrict__ deg, int e) {
    int i = blockIdx.x * blockDim.x + threadIdx.x;
    if (i < e) atomicAdd(&deg[dst[i]], 1);
}

__global__ void inv_deg_k(const int* __restrict__ deg, float* __restrict__ inv, int n) {
    int i = blockIdx.x * blockDim.x + threadIdx.x;
    if (i < n) {
        int d = deg[i];
        inv[i] = 1.0f / (float)(d > 0 ? d : 1);
    }
}

__global__ __launch_bounds__(256) void scan_part_k(const int* __restrict__ deg,
                                                   int* __restrict__ blockSums, int n) {
    __shared__ int red[256];
    int t = threadIdx.x;
    int base = blockIdx.x * SCAN_CHUNK + t * 4;
    int s = 0;
#pragma unroll
    for (int k = 0; k < 4; ++k) {
        int i = base + k;
        if (i < n) s += deg[i];
    }
    red[t] = s;
    __syncthreads();
    for (int off = 128; off > 0; off >>= 1) {
        if (t < off) red[t] += red[t + off];
        __syncthreads();
    }
    if (t == 0) blockSums[blockIdx.x] = red[0];
}

__global__ void scan_blocks_k(int* __restrict__ blockSums, int nb,
                              int* __restrict__ offs, int n) {
    if (threadIdx.x == 0 && blockIdx.x == 0) {
        int run = 0;
        for (int i = 0; i < nb; ++i) {
            int v = blockSums[i];
            blockSums[i] = run;
            run += v;
        }
        offs[n] = run;
    }
}

__global__ __launch_bounds__(256) void scan_final_k(const int* __restrict__ deg,
                                                    const int* __restrict__ blockSums,
                                                    int* __restrict__ offs,
                                                    int* __restrict__ cursor, int n) {
    __shared__ int red[256];
    int t = threadIdx.x;
    int base = blockIdx.x * SCAN_CHUNK + t * 4;
    int v[4];
    int s = 0;
#pragma unroll
    for (int k = 0; k < 4; ++k) {
        int i = base + k;
        v[k] = (i < n) ? deg[i] : 0;
        s += v[k];
    }
    red[t] = s;
    __syncthreads();
    for (int off = 1; off < 256; off <<= 1) {
        int x = (t >= off) ? red[t - off] : 0;
        __syncthreads();
        red[t] += x;
        __syncthreads();
    }
    int run = blockSums[blockIdx.x] + red[t] - s;
#pragma unroll
    for (int k = 0; k < 4; ++k) {
        int i = base + k;
        if (i < n) {
            offs[i] = run;
            cursor[i] = run;
            run += v[k];
        }
    }
}

__global__ void fill_csr_k(const int* __restrict__ src, const int* __restrict__ dst,
                           int* __restrict__ cursor, int* __restrict__ esrc, int e) {
    int i = blockIdx.x * blockDim.x + threadIdx.x;
    if (i < e) {
        int p = atomicAdd(&cursor[dst[i]], 1);
        esrc[p] = src[i];
    }
}

// ---------------- weight prep: W[K][NC] fp32 -> Wt hi/lo [NC][K] bf16 ----------------

__global__ void prep_w_k(const float* __restrict__ W, short* __restrict__ hi,
                         short* __restrict__ lo, int K, int NC) {
    int idx = blockIdx.x * 256 + threadIdx.x;
    if (idx >= K * NC) return;
    int k = idx / NC, n = idx % NC;
    float w = W[idx];
    unsigned u = __float_as_uint(w);
    short h = (short)(u >> 16);
    float res = w - __uint_as_float(u & 0xFFFF0000u);
    hi[(size_t)n * K + k] = h;
    lo[(size_t)n * K + k] = (short)(__float_as_uint(res) >> 16);
}

// ---------------- aggregation (one wave per node) ----------------

__global__ __launch_bounds__(256) void agg128_k(const float* __restrict__ h,
                                                const int* __restrict__ offs,
                                                const int* __restrict__ esrc,
                                                const float* __restrict__ inv,
                                                float* __restrict__ out, int n) {
    int wid = (int)((blockIdx.x * blockDim.x + threadIdx.x) >> 6);
    int lane = threadIdx.x & 63;
    if (wid >= n) return;
    int beg = offs[wid], end = offs[wid + 1];
    const float2* __restrict__ h2 = (const float2*)h;
    float ax = 0.f, ay = 0.f;
    int j = beg;
    for (; j + 2 <= end; j += 2) {
        int s0 = esrc[j], s1 = esrc[j + 1];
        float2 v0 = h2[(size_t)s0 * 64 + lane];
        float2 v1 = h2[(size_t)s1 * 64 + lane];
        ax += v0.x + v1.x;
        ay += v0.y + v1.y;
    }
    if (j < end) {
        float2 v = h2[(size_t)esrc[j] * 64 + lane];
        ax += v.x; ay += v.y;
    }
    float sc = inv[wid];
    float2 r; r.x = ax * sc; r.y = ay * sc;
    ((float2*)out)[(size_t)wid * 64 + lane] = r;
}

__global__ __launch_bounds__(256) void agg64_k(const float* __restrict__ t64,
                                               const int* __restrict__ offs,
                                               const int* __restrict__ esrc,
                                               const float* __restrict__ inv,
                                               const float* __restrict__ bias,
                                               float* __restrict__ out, int n) {
    int wid = (int)((blockIdx.x * blockDim.x + threadIdx.x) >> 6);
    int lane = threadIdx.x & 63;
    if (wid >= n) return;
    int beg = offs[wid], end = offs[wid + 1];
    float a = 0.f;
    int j = beg;
    for (; j + 2 <= end; j += 2) {
        int s0 = esrc[j], s1 = esrc[j + 1];
        a += t64[(size_t)s0 * 64 + lane] + t64[(size_t)s1 * 64 + lane];
    }
    if (j < end) a += t64[(size_t)esrc[j] * 64 + lane];
    out[(size_t)wid * 64 + lane] = a * inv[wid] + bias[lane];
}

// ---------------- MFMA GEMM: [M,128] fp32 x Wt(split-bf16) -> [M,NT*16] fp32 ----
// block = 4 waves; wave w owns rows [blk*64 + w*16, +16), all NT col-tiles.
// Split-bf16: a = ah + al (truncation + bf16 residual); D += ah*bh + al*bh + ah*bl.
// No LDS, no barriers.

template <int NT, bool HASB, bool RELU>
__global__ __launch_bounds__(256) void gemm_mfma_k(const float* __restrict__ A,
                                                   const short* __restrict__ Wth,
                                                   const short* __restrict__ Wtl,
                                                   const float* __restrict__ bias,
                                                   float* __restrict__ out, int M) {
    constexpr int NC = NT * 16;
    int wave = threadIdx.x >> 6;
    int lane = threadIdx.x & 63;
    int g = lane >> 4;    // 0..3 (k-group)
    int cl = lane & 15;   // 0..15 (row for A-frag, col for B-frag/D)
    int rowbase = blockIdx.x * 64 + wave * 16;
    int arow = rowbase + cl;
    if (arow >= M) arow = M - 1;  // clamp: loads stay in-bounds; stores are guarded
    const float* arowp = A + (size_t)arow * 128;

    f32x4 acc[NT];
#pragma unroll
    for (int t = 0; t < NT; ++t) acc[t] = (f32x4){0.f, 0.f, 0.f, 0.f};

#pragma unroll
    for (int ks = 0; ks < 4; ++ks) {
        int k0 = ks * 32 + g * 4;
        float4 aL = *(const float4*)(arowp + k0);
        float4 aH = *(const float4*)(arowp + k0 + 16);
        short8v ah, al;
        {
            float av0 = aL.x, av1 = aL.y, av2 = aL.z, av3 = aL.w;
            float av4 = aH.x, av5 = aH.y, av6 = aH.z, av7 = aH.w;
#define SPLIT1(J, V)                                                        \
            {                                                               \
                unsigned u = __float_as_uint(V);                            \
                ah[J] = (short)(u >> 16);                                   \
                float res = (V) - __uint_as_float(u & 0xFFFF0000u);         \
                al[J] = (short)(__float_as_uint(res) >> 16);                \
            }
            SPLIT1(0, av0) SPLIT1(1, av1) SPLIT1(2, av2) SPLIT1(3, av3)
            SPLIT1(4, av4) SPLIT1(5, av5) SPLIT1(6, av6) SPLIT1(7, av7)
#undef SPLIT1
        }
#pragma unroll
        for (int t = 0; t < NT; ++t) {
            const short* wph = Wth + (size_t)(t * 16 + cl) * 128 + k0;
            const short* wpl = Wtl + (size_t)(t * 16 + cl) * 128 + k0;
            short4v bhL = *(const short4v*)wph;
            short4v bhH = *(const short4v*)(wph + 16);
            short4v blL = *(const short4v*)wpl;
            short4v blH = *(const short4v*)(wpl + 16);
            short8v bh, bl;
#pragma unroll
            for (int j = 0; j < 4; ++j) {
                bh[j] = bhL[j]; bh[j + 4] = bhH[j];
                bl[j] = blL[j]; bl[j + 4] = blH[j];
            }
            acc[t] = __builtin_amdgcn_mfma_f32_16x16x32_bf16(ah, bh, acc[t], 0, 0, 0);
            acc[t] = __builtin_amdgcn_mfma_f32_16x16x32_bf16(al, bh, acc[t], 0, 0, 0);
            acc[t] = __builtin_amdgcn_mfma_f32_16x16x32_bf16(ah, bl, acc[t], 0, 0, 0);
        }
    }

#pragma unroll
    for (int t = 0; t < NT; ++t) {
        float b = 0.f;
        if (HASB) b = bias[t * 16 + cl];
#pragma unroll
        for (int r = 0; r < 4; ++r) {
            int gr = rowbase + g * 4 + r;
            if (gr < M) {
                float v = acc[t][r] + b;
                if (RELU) v = fmaxf(v, 0.f);
                out[(size_t)gr * NC + t * 16 + cl] = v;
            }
        }
    }
}

// ---------------- launch ----------------

extern "C" void kernel_launch(void* const* d_in, const int* in_sizes, int n_in,
                              void* d_out, int out_size, void* d_ws, size_t ws_size,
                              hipStream_t stream) {
    const int N = N_NODES, E = N_EDGES;
    const float* feat = (const float*)d_in[0];
    const int* src = (const int*)d_in[1];
    const int* dst = (const int*)d_in[2];
    const float* W1 = (const float*)d_in[3];
    const float* b1 = (const float*)d_in[4];
    const float* W2 = (const float*)d_in[5];
    const float* b2 = (const float*)d_in[6];
    const float* W3 = (const float*)d_in[7];
    const float* b3 = (const float*)d_in[8];
    float* out = (float*)d_out;

    const int nScanBlocks = (N + SCAN_CHUNK - 1) / SCAN_CHUNK;  // 49

    // workspace layout
    float* B0 = (float*)d_ws;                       // N*128 f32
    float* B1 = B0 + (size_t)N * 128;               // N*128 f32
    int* deg = (int*)(B1 + (size_t)N * 128);        // N
    float* invd = (float*)(deg + N);                // N
    int* offs = (int*)(invd + N);                   // N+2 (padded -> cursor 8B-aligned)
    int* cursor = offs + N + 2;                     // N
    int* esrc = cursor + N;                         // E
    int* blockSums = esrc + E;                      // nScanBlocks
    // Wt buffers alias `cursor` (free after fill_csr_k): 81920 shorts = 160KB <= N*4B
    short* Wt1h = (short*)cursor;
    short* Wt1l = Wt1h + 16384;
    short* Wt2h = Wt1l + 16384;
    short* Wt2l = Wt2h + 16384;
    short* Wt3h = Wt2l + 16384;
    short* Wt3l = Wt3h + 8192;

    // --- CSR build ---
    hipMemsetAsync(deg, 0, (size_t)N * sizeof(int), stream);
    count_deg_k<<<(E + 255) / 256, 256, 0, stream>>>(dst, deg, E);
    inv_deg_k<<<(N + 255) / 256, 256, 0, stream>>>(deg, invd, N);
    scan_part_k<<<nScanBlocks, 256, 0, stream>>>(deg, blockSums, N);
    scan_blocks_k<<<1, 64, 0, stream>>>(blockSums, nScanBlocks, offs, N);
    scan_final_k<<<nScanBlocks, 256, 0, stream>>>(deg, blockSums, offs, cursor, N);
    fill_csr_k<<<(E + 255) / 256, 256, 0, stream>>>(src, dst, cursor, esrc, E);

    // --- weight prep (after fill_csr: Wt aliases cursor) ---
    prep_w_k<<<(128 * 128 + 255) / 256, 256, 0, stream>>>(W1, Wt1h, Wt1l, 128, 128);
    prep_w_k<<<(128 * 128 + 255) / 256, 256, 0, stream>>>(W2, Wt2h, Wt2l, 128, 128);
    prep_w_k<<<(128 * 64 + 255) / 256, 256, 0, stream>>>(W3, Wt3h, Wt3l, 128, 64);

    const int aggGrid = (N + 3) / 4;        // 4 waves (nodes) per 256-thread block
    const int gemmGrid = (N + 63) / 64;     // 64 rows per block

    // --- layer 1 ---
    agg128_k<<<aggGrid, 256, 0, stream>>>(feat, offs, esrc, invd, B0, N);
    gemm_mfma_k<8, true, true><<<gemmGrid, 256, 0, stream>>>(B0, Wt1h, Wt1l, b1, B1, N);
    // --- layer 2 ---
    agg128_k<<<aggGrid, 256, 0, stream>>>(B1, offs, esrc, invd, B0, N);
    gemm_mfma_k<8, true, true><<<gemmGrid, 256, 0, stream>>>(B0, Wt2h, Wt2l, b2, B1, N);
    // --- layer 3: T = h2 @ W3, then 64-wide aggregate + b3 ---
    gemm_mfma_k<4, false, false><<<gemmGrid, 256, 0, stream>>>(B1, Wt3h, Wt3l, nullptr, B0, N);
    agg64_k<<<aggGrid, 256, 0, stream>>>(B0, offs, esrc, invd, b3, out, N);
}

// Round 5
// 430.691 us; speedup vs baseline: 1.0941x; 1.0941x over previous
//
#include <hip/hip_runtime.h>
#include <stdint.h>

// GCN: 3-layer GraphConv (norm='right'), N=50000, E=600000, 128->128->128->64.
//
// R1: hierarchical scan (scan_k 110us -> ~5us).                 [442us total]
// R3: GEMM -> MFMA split-bf16 (a=ah+al, 3x mfma_16x16x32_bf16). Correct but
//     NEUTRAL (68us, MfmaUtil 2.6%): latency-bound, 3128 waves, long chains.
// R4: parallelism fix. GEMM col-split (each block 64 rows x 32 cols, grid x4,
//     24 MFMA/40 loads per wave). agg128: 2 nodes/wave, float4/lane, unroll 4.
//     agg64: 4 nodes/wave, float4/lane.

#define N_NODES 50000
#define N_EDGES 600000
#define SCAN_CHUNK 1024

typedef __attribute__((ext_vector_type(8))) short short8v;
typedef __attribute__((ext_vector_type(4))) short short4v;
typedef __attribute__((ext_vector_type(4))) float f32x4;

// ---------------- CSR build ----------------

__global__ void count_deg_k(const int* __restrict__ dst, int* __restrict__ deg, int e) {
    int i = blockIdx.x * blockDim.x + threadIdx.x;
    if (i < e) atomicAdd(&deg[dst[i]], 1);
}

__global__ void inv_deg_k(const int* __restrict__ deg, float* __restrict__ inv, int n) {
    int i = blockIdx.x * blockDim.x + threadIdx.x;
    if (i < n) {
        int d = deg[i];
        inv[i] = 1.0f / (float)(d > 0 ? d : 1);
    }
}

__global__ __launch_bounds__(256) void scan_part_k(const int* __restrict__ deg,
                                                   int* __restrict__ blockSums, int n) {
    __shared__ int red[256];
    int t = threadIdx.x;
    int base = blockIdx.x * SCAN_CHUNK + t * 4;
    int s = 0;
#pragma unroll
    for (int k = 0; k < 4; ++k) {
        int i = base + k;
        if (i < n) s += deg[i];
    }
    red[t] = s;
    __syncthreads();
    for (int off = 128; off > 0; off >>= 1) {
        if (t < off) red[t] += red[t + off];
        __syncthreads();
    }
    if (t == 0) blockSums[blockIdx.x] = red[0];
}

__global__ void scan_blocks_k(int* __restrict__ blockSums, int nb,
                              int* __restrict__ offs, int n) {
    if (threadIdx.x == 0 && blockIdx.x == 0) {
        int run = 0;
        for (int i = 0; i < nb; ++i) {
            int v = blockSums[i];
            blockSums[i] = run;
            run += v;
        }
        offs[n] = run;
    }
}

__global__ __launch_bounds__(256) void scan_final_k(const int* __restrict__ deg,
                                                    const int* __restrict__ blockSums,
                                                    int* __restrict__ offs,
                                                    int* __restrict__ cursor, int n) {
    __shared__ int red[256];
    int t = threadIdx.x;
    int base = blockIdx.x * SCAN_CHUNK + t * 4;
    int v[4];
    int s = 0;
#pragma unroll
    for (int k = 0; k < 4; ++k) {
        int i = base + k;
        v[k] = (i < n) ? deg[i] : 0;
        s += v[k];
    }
    red[t] = s;
    __syncthreads();
    for (int off = 1; off < 256; off <<= 1) {
        int x = (t >= off) ? red[t - off] : 0;
        __syncthreads();
        red[t] += x;
        __syncthreads();
    }
    int run = blockSums[blockIdx.x] + red[t] - s;
#pragma unroll
    for (int k = 0; k < 4; ++k) {
        int i = base + k;
        if (i < n) {
            offs[i] = run;
            cursor[i] = run;
            run += v[k];
        }
    }
}

__global__ void fill_csr_k(const int* __restrict__ src, const int* __restrict__ dst,
                           int* __restrict__ cursor, int* __restrict__ esrc, int e) {
    int i = blockIdx.x * blockDim.x + threadIdx.x;
    if (i < e) {
        int p = atomicAdd(&cursor[dst[i]], 1);
        esrc[p] = src[i];
    }
}

// ---------------- weight prep: W[K][NC] fp32 -> Wt hi/lo [NC][K] bf16 ----------------

__global__ void prep_w_k(const float* __restrict__ W, short* __restrict__ hi,
                         short* __restrict__ lo, int K, int NC) {
    int idx = blockIdx.x * 256 + threadIdx.x;
    if (idx >= K * NC) return;
    int k = idx / NC, n = idx % NC;
    float w = W[idx];
    unsigned u = __float_as_uint(w);
    short h = (short)(u >> 16);
    float res = w - __uint_as_float(u & 0xFFFF0000u);
    hi[(size_t)n * K + k] = h;
    lo[(size_t)n * K + k] = (short)(__float_as_uint(res) >> 16);
}

// ---------------- aggregation ----------------

// 128-wide: 2 nodes per wave (32 lanes each), float4 (16B) per lane, unroll 4.
__global__ __launch_bounds__(256) void agg128_k(const float* __restrict__ h,
                                                const int* __restrict__ offs,
                                                const int* __restrict__ esrc,
                                                const float* __restrict__ inv,
                                                float* __restrict__ out, int n) {
    int gt = blockIdx.x * 256 + threadIdx.x;
    int wv = gt >> 6;
    int half = (threadIdx.x >> 5) & 1;
    int l5 = threadIdx.x & 31;
    int node = wv * 2 + half;
    if (node >= n) return;
    int beg = offs[node], end = offs[node + 1];
    const float4* __restrict__ h4 = (const float4*)h;
    float4 a = {0.f, 0.f, 0.f, 0.f};
    int j = beg;
    for (; j + 4 <= end; j += 4) {
        int s0 = esrc[j], s1 = esrc[j + 1], s2 = esrc[j + 2], s3 = esrc[j + 3];
        float4 v0 = h4[(size_t)s0 * 32 + l5];
        float4 v1 = h4[(size_t)s1 * 32 + l5];
        float4 v2 = h4[(size_t)s2 * 32 + l5];
        float4 v3 = h4[(size_t)s3 * 32 + l5];
        a.x += (v0.x + v1.x) + (v2.x + v3.x);
        a.y += (v0.y + v1.y) + (v2.y + v3.y);
        a.z += (v0.z + v1.z) + (v2.z + v3.z);
        a.w += (v0.w + v1.w) + (v2.w + v3.w);
    }
    for (; j < end; ++j) {
        float4 v = h4[(size_t)esrc[j] * 32 + l5];
        a.x += v.x; a.y += v.y; a.z += v.z; a.w += v.w;
    }
    float sc = inv[node];
    float4 r; r.x = a.x * sc; r.y = a.y * sc; r.z = a.z * sc; r.w = a.w * sc;
    ((float4*)out)[(size_t)node * 32 + l5] = r;
}

// 64-wide: 4 nodes per wave (16 lanes each), float4 per lane; fused bias; final out.
__global__ __launch_bounds__(256) void agg64_k(const float* __restrict__ t64,
                                               const int* __restrict__ offs,
                                               const int* __restrict__ esrc,
                                               const float* __restrict__ inv,
                                               const float* __restrict__ bias,
                                               float* __restrict__ out, int n) {
    int gt = blockIdx.x * 256 + threadIdx.x;
    int wv = gt >> 6;
    int q = (threadIdx.x >> 4) & 3;
    int l4 = threadIdx.x & 15;
    int node = wv * 4 + q;
    if (node >= n) return;
    int beg = offs[node], end = offs[node + 1];
    const float4* __restrict__ h4 = (const float4*)t64;
    float4 a = {0.f, 0.f, 0.f, 0.f};
    int j = beg;
    for (; j + 4 <= end; j += 4) {
        int s0 = esrc[j], s1 = esrc[j + 1], s2 = esrc[j + 2], s3 = esrc[j + 3];
        float4 v0 = h4[(size_t)s0 * 16 + l4];
        float4 v1 = h4[(size_t)s1 * 16 + l4];
        float4 v2 = h4[(size_t)s2 * 16 + l4];
        float4 v3 = h4[(size_t)s3 * 16 + l4];
        a.x += (v0.x + v1.x) + (v2.x + v3.x);
        a.y += (v0.y + v1.y) + (v2.y + v3.y);
        a.z += (v0.z + v1.z) + (v2.z + v3.z);
        a.w += (v0.w + v1.w) + (v2.w + v3.w);
    }
    for (; j < end; ++j) {
        float4 v = h4[(size_t)esrc[j] * 16 + l4];
        a.x += v.x; a.y += v.y; a.z += v.z; a.w += v.w;
    }
    float sc = inv[node];
    float4 b = ((const float4*)bias)[l4];
    float4 r;
    r.x = a.x * sc + b.x; r.y = a.y * sc + b.y;
    r.z = a.z * sc + b.z; r.w = a.w * sc + b.w;
    ((float4*)out)[(size_t)node * 16 + l4] = r;
}

// ---------------- MFMA GEMM: [M,128] fp32 x Wt(split-bf16) -> [M,NCTOT] fp32 ----
// Block = 4 waves = 64 rows x 32 cols (one col-tile). grid = rowBlocks * (NCTOT/32).
// Consecutive blockIdx share rows (A locality). Split-bf16: D += ah*bh+al*bh+ah*bl.
// Per wave: 24 MFMA, ~40 VMEM loads. No LDS, no barriers.

template <int NCTOT, bool HASB, bool RELU>
__global__ __launch_bounds__(256) void gemm_mfma_k(const float* __restrict__ A,
                                                   const short* __restrict__ Wth,
                                                   const short* __restrict__ Wtl,
                                                   const float* __restrict__ bias,
                                                   float* __restrict__ out, int M) {
    constexpr int CT = NCTOT / 32;
    int rowblk = blockIdx.x / CT;
    int colblk = blockIdx.x % CT;
    int col0 = colblk * 32;
    int wave = threadIdx.x >> 6;
    int lane = threadIdx.x & 63;
    int g = lane >> 4;    // 0..3 (k-group)
    int cl = lane & 15;   // 0..15 (row for A-frag, col for B-frag/D)
    int rowbase = rowblk * 64 + wave * 16;
    int arow = rowbase + cl;
    if (arow >= M) arow = M - 1;  // clamp loads; stores guarded
    const float* arowp = A + (size_t)arow * 128;

    f32x4 acc0 = {0.f, 0.f, 0.f, 0.f}, acc1 = {0.f, 0.f, 0.f, 0.f};

#pragma unroll
    for (int ks = 0; ks < 4; ++ks) {
        int k0 = ks * 32 + g * 4;
        float4 aL = *(const float4*)(arowp + k0);
        float4 aH = *(const float4*)(arowp + k0 + 16);
        short8v ah, al;
        {
#define SPLIT1(J, V)                                                        \
            {                                                               \
                unsigned u = __float_as_uint(V);                            \
                ah[J] = (short)(u >> 16);                                   \
                float res = (V) - __uint_as_float(u & 0xFFFF0000u);         \
                al[J] = (short)(__float_as_uint(res) >> 16);                \
            }
            SPLIT1(0, aL.x) SPLIT1(1, aL.y) SPLIT1(2, aL.z) SPLIT1(3, aL.w)
            SPLIT1(4, aH.x) SPLIT1(5, aH.y) SPLIT1(6, aH.z) SPLIT1(7, aH.w)
#undef SPLIT1
        }
#pragma unroll
        for (int t = 0; t < 2; ++t) {
            const short* wph = Wth + (size_t)(col0 + t * 16 + cl) * 128 + k0;
            const short* wpl = Wtl + (size_t)(col0 + t * 16 + cl) * 128 + k0;
            short4v bhL = *(const short4v*)wph;
            short4v bhH = *(const short4v*)(wph + 16);
            short4v blL = *(const short4v*)wpl;
            short4v blH = *(const short4v*)(wpl + 16);
            short8v bh, bl;
#pragma unroll
            for (int j = 0; j < 4; ++j) {
                bh[j] = bhL[j]; bh[j + 4] = bhH[j];
                bl[j] = blL[j]; bl[j + 4] = blH[j];
            }
            f32x4 acc = (t == 0) ? acc0 : acc1;
            acc = __builtin_amdgcn_mfma_f32_16x16x32_bf16(ah, bh, acc, 0, 0, 0);
            acc = __builtin_amdgcn_mfma_f32_16x16x32_bf16(al, bh, acc, 0, 0, 0);
            acc = __builtin_amdgcn_mfma_f32_16x16x32_bf16(ah, bl, acc, 0, 0, 0);
            if (t == 0) acc0 = acc; else acc1 = acc;
        }
    }

#pragma unroll
    for (int t = 0; t < 2; ++t) {
        f32x4 acc = (t == 0) ? acc0 : acc1;
        float b = 0.f;
        if (HASB) b = bias[col0 + t * 16 + cl];
#pragma unroll
        for (int r = 0; r < 4; ++r) {
            int gr = rowbase + g * 4 + r;
            if (gr < M) {
                float v = acc[r] + b;
                if (RELU) v = fmaxf(v, 0.f);
                out[(size_t)gr * NCTOT + col0 + t * 16 + cl] = v;
            }
        }
    }
}

// ---------------- launch ----------------

extern "C" void kernel_launch(void* const* d_in, const int* in_sizes, int n_in,
                              void* d_out, int out_size, void* d_ws, size_t ws_size,
                              hipStream_t stream) {
    const int N = N_NODES, E = N_EDGES;
    const float* feat = (const float*)d_in[0];
    const int* src = (const int*)d_in[1];
    const int* dst = (const int*)d_in[2];
    const float* W1 = (const float*)d_in[3];
    const float* b1 = (const float*)d_in[4];
    const float* W2 = (const float*)d_in[5];
    const float* b2 = (const float*)d_in[6];
    const float* W3 = (const float*)d_in[7];
    const float* b3 = (const float*)d_in[8];
    float* out = (float*)d_out;

    const int nScanBlocks = (N + SCAN_CHUNK - 1) / SCAN_CHUNK;  // 49

    // workspace layout
    float* B0 = (float*)d_ws;                       // N*128 f32
    float* B1 = B0 + (size_t)N * 128;               // N*128 f32
    int* deg = (int*)(B1 + (size_t)N * 128);        // N
    float* invd = (float*)(deg + N);                // N
    int* offs = (int*)(invd + N);                   // N+2 (pad -> cursor 8B-aligned)
    int* cursor = offs + N + 2;                     // N
    int* esrc = cursor + N;                         // E
    int* blockSums = esrc + E;                      // nScanBlocks
    // Wt buffers alias `cursor` (free after fill_csr_k): 160KB <= N*4B
    short* Wt1h = (short*)cursor;
    short* Wt1l = Wt1h + 16384;
    short* Wt2h = Wt1l + 16384;
    short* Wt2l = Wt2h + 16384;
    short* Wt3h = Wt2l + 16384;
    short* Wt3l = Wt3h + 8192;

    // --- CSR build ---
    hipMemsetAsync(deg, 0, (size_t)N * sizeof(int), stream);
    count_deg_k<<<(E + 255) / 256, 256, 0, stream>>>(dst, deg, E);
    inv_deg_k<<<(N + 255) / 256, 256, 0, stream>>>(deg, invd, N);
    scan_part_k<<<nScanBlocks, 256, 0, stream>>>(deg, blockSums, N);
    scan_blocks_k<<<1, 64, 0, stream>>>(blockSums, nScanBlocks, offs, N);
    scan_final_k<<<nScanBlocks, 256, 0, stream>>>(deg, blockSums, offs, cursor, N);
    fill_csr_k<<<(E + 255) / 256, 256, 0, stream>>>(src, dst, cursor, esrc, E);

    // --- weight prep (after fill_csr: Wt aliases cursor) ---
    prep_w_k<<<(128 * 128 + 255) / 256, 256, 0, stream>>>(W1, Wt1h, Wt1l, 128, 128);
    prep_w_k<<<(128 * 128 + 255) / 256, 256, 0, stream>>>(W2, Wt2h, Wt2l, 128, 128);
    prep_w_k<<<(128 * 64 + 255) / 256, 256, 0, stream>>>(W3, Wt3h, Wt3l, 128, 64);

    const int agg128Grid = (N + 7) / 8;      // 2 nodes/wave * 4 waves
    const int agg64Grid = (N + 15) / 16;     // 4 nodes/wave * 4 waves
    const int rowBlocks = (N + 63) / 64;     // 782

    // --- layer 1 ---
    agg128_k<<<agg128Grid, 256, 0, stream>>>(feat, offs, esrc, invd, B0, N);
    gemm_mfma_k<128, true, true><<<rowBlocks * 4, 256, 0, stream>>>(B0, Wt1h, Wt1l, b1, B1, N);
    // --- layer 2 ---
    agg128_k<<<agg128Grid, 256, 0, stream>>>(B1, offs, esrc, invd, B0, N);
    gemm_mfma_k<128, true, true><<<rowBlocks * 4, 256, 0, stream>>>(B0, Wt2h, Wt2l, b2, B1, N);
    // --- layer 3: T = h2 @ W3, then 64-wide aggregate + b3 ---
    gemm_mfma_k<64, false, false><<<rowBlocks * 2, 256, 0, stream>>>(B1, Wt3h, Wt3l, nullptr, B0, N);
    agg64_k<<<agg64Grid, 256, 0, stream>>>(B0, offs, esrc, invd, b3, out, N);
}

// Round 7
// 337.473 us; speedup vs baseline: 1.3963x; 1.2762x over previous
//
#include <hip/hip_runtime.h>
#include <stdint.h>

// GCN: 3-layer GraphConv (norm='right'), N=50000, E=600000, 128->128->128->64.
//
// R1: hierarchical scan (scan_k 110us -> ~5us).                 [442us total]
// R3: GEMM -> MFMA split-bf16 (a=ah+al, 3x mfma_16x16x32_bf16). NEUTRAL:
//     latency-bound (3128 waves, long chains).
// R4: grid x4 + agg float4. Occupancy 25->70% but gemm STILL 64us:
//     TA/L1 transaction-bound (B loads: 64 lanes x 256B stride = 64 segs/instr,
//     ~2048 segs/wave -> ~42us floor).                          [431us total]
// R5: (a) fragment-major W: B-frag = coalesced dwordx4/lane (16 segs, 8x fewer
//     transactions); (b) bijective XCD swizzle: contiguous rows per XCD ->
//     per-XCD A slice 3.2MB fits 4MB L2 (A fetched once).
// R6: resubmit (GPU acquisition timeout, no data).

#define N_NODES 50000
#define N_EDGES 600000
#define SCAN_CHUNK 1024

typedef __attribute__((ext_vector_type(8))) short short8v;
typedef __attribute__((ext_vector_type(4))) float f32x4;

// ---------------- CSR build ----------------

__global__ void count_deg_k(const int* __restrict__ dst, int* __restrict__ deg, int e) {
    int i = blockIdx.x * blockDim.x + threadIdx.x;
    if (i < e) atomicAdd(&deg[dst[i]], 1);
}

__global__ void inv_deg_k(const int* __restrict__ deg, float* __restrict__ inv, int n) {
    int i = blockIdx.x * blockDim.x + threadIdx.x;
    if (i < n) {
        int d = deg[i];
        inv[i] = 1.0f / (float)(d > 0 ? d : 1);
    }
}

__global__ __launch_bounds__(256) void scan_part_k(const int* __restrict__ deg,
                                                   int* __restrict__ blockSums, int n) {
    __shared__ int red[256];
    int t = threadIdx.x;
    int base = blockIdx.x * SCAN_CHUNK + t * 4;
    int s = 0;
#pragma unroll
    for (int k = 0; k < 4; ++k) {
        int i = base + k;
        if (i < n) s += deg[i];
    }
    red[t] = s;
    __syncthreads();
    for (int off = 128; off > 0; off >>= 1) {
        if (t < off) red[t] += red[t + off];
        __syncthreads();
    }
    if (t == 0) blockSums[blockIdx.x] = red[0];
}

__global__ void scan_blocks_k(int* __restrict__ blockSums, int nb,
                              int* __restrict__ offs, int n) {
    if (threadIdx.x == 0 && blockIdx.x == 0) {
        int run = 0;
        for (int i = 0; i < nb; ++i) {
            int v = blockSums[i];
            blockSums[i] = run;
            run += v;
        }
        offs[n] = run;
    }
}

__global__ __launch_bounds__(256) void scan_final_k(const int* __restrict__ deg,
                                                    const int* __restrict__ blockSums,
                                                    int* __restrict__ offs,
                                                    int* __restrict__ cursor, int n) {
    __shared__ int red[256];
    int t = threadIdx.x;
    int base = blockIdx.x * SCAN_CHUNK + t * 4;
    int v[4];
    int s = 0;
#pragma unroll
    for (int k = 0; k < 4; ++k) {
        int i = base + k;
        v[k] = (i < n) ? deg[i] : 0;
        s += v[k];
    }
    red[t] = s;
    __syncthreads();
    for (int off = 1; off < 256; off <<= 1) {
        int x = (t >= off) ? red[t - off] : 0;
        __syncthreads();
        red[t] += x;
        __syncthreads();
    }
    int run = blockSums[blockIdx.x] + red[t] - s;
#pragma unroll
    for (int k = 0; k < 4; ++k) {
        int i = base + k;
        if (i < n) {
            offs[i] = run;
            cursor[i] = run;
            run += v[k];
        }
    }
}

__global__ void fill_csr_k(const int* __restrict__ src, const int* __restrict__ dst,
                           int* __restrict__ cursor, int* __restrict__ esrc, int e) {
    int i = blockIdx.x * blockDim.x + threadIdx.x;
    if (i < e) {
        int p = atomicAdd(&cursor[dst[i]], 1);
        esrc[p] = src[i];
    }
}

// ---- weight prep: W[K][NC] fp32 -> fragment-major split-bf16 hi/lo ----
// Layout: for tile T (NC/16), kstep ks (4), lane l (64): 8 bf16 contiguous at
// (((T*4+ks)*64)+l)*8. Lane l=g*16+cl holds W[k][T*16+cl], k=ks*32+g*4+(j&3)+16*(j>>2).

__global__ void prep_wf_k(const float* __restrict__ W, short* __restrict__ hiF,
                          short* __restrict__ loF, int NC) {
    int idx = blockIdx.x * 256 + threadIdx.x;
    int total = (NC / 16) * 4 * 64;
    if (idx >= total) return;
    int lane = idx & 63;
    int ks = (idx >> 6) & 3;
    int T = idx >> 8;
    int g = lane >> 4, cl = lane & 15;
    int col = T * 16 + cl;
    short8v h, l;
#pragma unroll
    for (int j = 0; j < 8; ++j) {
        int k = ks * 32 + g * 4 + (j & 3) + ((j >> 2) << 4);
        float w = W[(size_t)k * NC + col];
        unsigned u = __float_as_uint(w);
        h[j] = (short)(u >> 16);
        float res = w - __uint_as_float(u & 0xFFFF0000u);
        l[j] = (short)(__float_as_uint(res) >> 16);
    }
    ((short8v*)hiF)[idx] = h;
    ((short8v*)loF)[idx] = l;
}

// ---------------- aggregation ----------------

// 128-wide: 2 nodes per wave (32 lanes each), float4 (16B) per lane, unroll 4.
__global__ __launch_bounds__(256) void agg128_k(const float* __restrict__ h,
                                                const int* __restrict__ offs,
                                                const int* __restrict__ esrc,
                                                const float* __restrict__ inv,
                                                float* __restrict__ out, int n) {
    int gt = blockIdx.x * 256 + threadIdx.x;
    int wv = gt >> 6;
    int half = (threadIdx.x >> 5) & 1;
    int l5 = threadIdx.x & 31;
    int node = wv * 2 + half;
    if (node >= n) return;
    int beg = offs[node], end = offs[node + 1];
    const float4* __restrict__ h4 = (const float4*)h;
    float4 a = {0.f, 0.f, 0.f, 0.f};
    int j = beg;
    for (; j + 4 <= end; j += 4) {
        int s0 = esrc[j], s1 = esrc[j + 1], s2 = esrc[j + 2], s3 = esrc[j + 3];
        float4 v0 = h4[(size_t)s0 * 32 + l5];
        float4 v1 = h4[(size_t)s1 * 32 + l5];
        float4 v2 = h4[(size_t)s2 * 32 + l5];
        float4 v3 = h4[(size_t)s3 * 32 + l5];
        a.x += (v0.x + v1.x) + (v2.x + v3.x);
        a.y += (v0.y + v1.y) + (v2.y + v3.y);
        a.z += (v0.z + v1.z) + (v2.z + v3.z);
        a.w += (v0.w + v1.w) + (v2.w + v3.w);
    }
    for (; j < end; ++j) {
        float4 v = h4[(size_t)esrc[j] * 32 + l5];
        a.x += v.x; a.y += v.y; a.z += v.z; a.w += v.w;
    }
    float sc = inv[node];
    float4 r; r.x = a.x * sc; r.y = a.y * sc; r.z = a.z * sc; r.w = a.w * sc;
    ((float4*)out)[(size_t)node * 32 + l5] = r;
}

// 64-wide: 4 nodes per wave (16 lanes each), float4 per lane; fused bias; final out.
__global__ __launch_bounds__(256) void agg64_k(const float* __restrict__ t64,
                                               const int* __restrict__ offs,
                                               const int* __restrict__ esrc,
                                               const float* __restrict__ inv,
                                               const float* __restrict__ bias,
                                               float* __restrict__ out, int n) {
    int gt = blockIdx.x * 256 + threadIdx.x;
    int wv = gt >> 6;
    int q = (threadIdx.x >> 4) & 3;
    int l4 = threadIdx.x & 15;
    int node = wv * 4 + q;
    if (node >= n) return;
    int beg = offs[node], end = offs[node + 1];
    const float4* __restrict__ h4 = (const float4*)t64;
    float4 a = {0.f, 0.f, 0.f, 0.f};
    int j = beg;
    for (; j + 4 <= end; j += 4) {
        int s0 = esrc[j], s1 = esrc[j + 1], s2 = esrc[j + 2], s3 = esrc[j + 3];
        float4 v0 = h4[(size_t)s0 * 16 + l4];
        float4 v1 = h4[(size_t)s1 * 16 + l4];
        float4 v2 = h4[(size_t)s2 * 16 + l4];
        float4 v3 = h4[(size_t)s3 * 16 + l4];
        a.x += (v0.x + v1.x) + (v2.x + v3.x);
        a.y += (v0.y + v1.y) + (v2.y + v3.y);
        a.z += (v0.z + v1.z) + (v2.z + v3.z);
        a.w += (v0.w + v1.w) + (v2.w + v3.w);
    }
    for (; j < end; ++j) {
        float4 v = h4[(size_t)esrc[j] * 16 + l4];
        a.x += v.x; a.y += v.y; a.z += v.z; a.w += v.w;
    }
    float sc = inv[node];
    float4 b = ((const float4*)bias)[l4];
    float4 r;
    r.x = a.x * sc + b.x; r.y = a.y * sc + b.y;
    r.z = a.z * sc + b.z; r.w = a.w * sc + b.w;
    ((float4*)out)[(size_t)node * 16 + l4] = r;
}

// ---------------- MFMA GEMM: [M,128] fp32 x WF(frag-major split-bf16) ----------
// Block = 4 waves = 64 rows x 32 cols. Bijective XCD swizzle: each XCD owns a
// contiguous run of (rowblk,colblk) pairs -> A slice fits per-XCD L2.
// B-frag loads are fully coalesced dwordx4/lane. No LDS, no barriers.

template <int NCTOT, bool HASB, bool RELU>
__global__ __launch_bounds__(256) void gemm_mfma_k(const float* __restrict__ A,
                                                   const short* __restrict__ WhF,
                                                   const short* __restrict__ WlF,
                                                   const float* __restrict__ bias,
                                                   float* __restrict__ out, int M) {
    constexpr int CT = NCTOT / 32;
    // bijective XCD swizzle (guide m204): xcd = b%8 gets contiguous sw range
    int nwg = gridDim.x;
    int b = blockIdx.x;
    int qq = nwg >> 3, rr = nwg & 7;
    int xcd = b & 7, ix = b >> 3;
    int sw = (xcd < rr ? xcd * (qq + 1) : rr * (qq + 1) + (xcd - rr) * qq) + ix;
    int rowblk = sw / CT;
    int colblk = sw % CT;

    int wave = threadIdx.x >> 6;
    int lane = threadIdx.x & 63;
    int g = lane >> 4;    // 0..3 (k-group)
    int cl = lane & 15;   // 0..15 (row for A-frag, col for B-frag/D)
    int rowbase = rowblk * 64 + wave * 16;
    int arow = rowbase + cl;
    if (arow >= M) arow = M - 1;  // clamp loads; stores guarded
    const float* arowp = A + (size_t)arow * 128;

    f32x4 acc0 = {0.f, 0.f, 0.f, 0.f}, acc1 = {0.f, 0.f, 0.f, 0.f};

#pragma unroll
    for (int ks = 0; ks < 4; ++ks) {
        int k0 = ks * 32 + g * 4;
        float4 aL = *(const float4*)(arowp + k0);
        float4 aH = *(const float4*)(arowp + k0 + 16);
        short8v ah, al;
        {
#define SPLIT1(J, V)                                                        \
            {                                                               \
                unsigned u = __float_as_uint(V);                            \
                ah[J] = (short)(u >> 16);                                   \
                float res = (V) - __uint_as_float(u & 0xFFFF0000u);         \
                al[J] = (short)(__float_as_uint(res) >> 16);                \
            }
            SPLIT1(0, aL.x) SPLIT1(1, aL.y) SPLIT1(2, aL.z) SPLIT1(3, aL.w)
            SPLIT1(4, aH.x) SPLIT1(5, aH.y) SPLIT1(6, aH.z) SPLIT1(7, aH.w)
#undef SPLIT1
        }
#pragma unroll
        for (int t = 0; t < 2; ++t) {
            int tileIdx = colblk * 2 + t;
            size_t fo = ((size_t)(tileIdx * 4 + ks) * 64 + lane) * 8;
            short8v bh = *(const short8v*)(WhF + fo);
            short8v bl = *(const short8v*)(WlF + fo);
            f32x4 acc = (t == 0) ? acc0 : acc1;
            acc = __builtin_amdgcn_mfma_f32_16x16x32_bf16(ah, bh, acc, 0, 0, 0);
            acc = __builtin_amdgcn_mfma_f32_16x16x32_bf16(al, bh, acc, 0, 0, 0);
            acc = __builtin_amdgcn_mfma_f32_16x16x32_bf16(ah, bl, acc, 0, 0, 0);
            if (t == 0) acc0 = acc; else acc1 = acc;
        }
    }

#pragma unroll
    for (int t = 0; t < 2; ++t) {
        f32x4 acc = (t == 0) ? acc0 : acc1;
        int col = colblk * 32 + t * 16 + cl;
        float bv = 0.f;
        if (HASB) bv = bias[col];
#pragma unroll
        for (int r = 0; r < 4; ++r) {
            int gr = rowbase + g * 4 + r;
            if (gr < M) {
                float v = acc[r] + bv;
                if (RELU) v = fmaxf(v, 0.f);
                out[(size_t)gr * NCTOT + col] = v;
            }
        }
    }
}

// ---------------- launch ----------------

extern "C" void kernel_launch(void* const* d_in, const int* in_sizes, int n_in,
                              void* d_out, int out_size, void* d_ws, size_t ws_size,
                              hipStream_t stream) {
    const int N = N_NODES, E = N_EDGES;
    const float* feat = (const float*)d_in[0];
    const int* src = (const int*)d_in[1];
    const int* dst = (const int*)d_in[2];
    const float* W1 = (const float*)d_in[3];
    const float* b1 = (const float*)d_in[4];
    const float* W2 = (const float*)d_in[5];
    const float* b2 = (const float*)d_in[6];
    const float* W3 = (const float*)d_in[7];
    const float* b3 = (const float*)d_in[8];
    float* out = (float*)d_out;

    const int nScanBlocks = (N + SCAN_CHUNK - 1) / SCAN_CHUNK;  // 49

    // workspace layout
    float* B0 = (float*)d_ws;                       // N*128 f32
    float* B1 = B0 + (size_t)N * 128;               // N*128 f32
    int* deg = (int*)(B1 + (size_t)N * 128);        // N
    float* invd = (float*)(deg + N);                // N
    int* offs = (int*)(invd + N);                   // N+2 (pad -> cursor 8B-aligned)
    int* cursor = offs + N + 2;                     // N
    int* esrc = cursor + N;                         // E
    int* blockSums = esrc + E;                      // nScanBlocks
    // WF buffers alias `cursor` (free after fill_csr_k): 160KB <= N*4B
    short* W1h = (short*)cursor;
    short* W1l = W1h + 16384;
    short* W2h = W1l + 16384;
    short* W2l = W2h + 16384;
    short* W3h = W2l + 16384;
    short* W3l = W3h + 8192;

    // --- CSR build ---
    hipMemsetAsync(deg, 0, (size_t)N * sizeof(int), stream);
    count_deg_k<<<(E + 255) / 256, 256, 0, stream>>>(dst, deg, E);
    inv_deg_k<<<(N + 255) / 256, 256, 0, stream>>>(deg, invd, N);
    scan_part_k<<<nScanBlocks, 256, 0, stream>>>(deg, blockSums, N);
    scan_blocks_k<<<1, 64, 0, stream>>>(blockSums, nScanBlocks, offs, N);
    scan_final_k<<<nScanBlocks, 256, 0, stream>>>(deg, blockSums, offs, cursor, N);
    fill_csr_k<<<(E + 255) / 256, 256, 0, stream>>>(src, dst, cursor, esrc, E);

    // --- weight prep (after fill_csr: WF aliases cursor) ---
    prep_wf_k<<<(128 * 16 + 255) / 256, 256, 0, stream>>>(W1, W1h, W1l, 128);
    prep_wf_k<<<(128 * 16 + 255) / 256, 256, 0, stream>>>(W2, W2h, W2l, 128);
    prep_wf_k<<<(64 * 16 + 255) / 256, 256, 0, stream>>>(W3, W3h, W3l, 64);

    const int agg128Grid = (N + 7) / 8;      // 2 nodes/wave * 4 waves
    const int agg64Grid = (N + 15) / 16;     // 4 nodes/wave * 4 waves
    const int rowBlocks = (N + 63) / 64;     // 782

    // --- layer 1 ---
    agg128_k<<<agg128Grid, 256, 0, stream>>>(feat, offs, esrc, invd, B0, N);
    gemm_mfma_k<128, true, true><<<rowBlocks * 4, 256, 0, stream>>>(B0, W1h, W1l, b1, B1, N);
    // --- layer 2 ---
    agg128_k<<<agg128Grid, 256, 0, stream>>>(B1, offs, esrc, invd, B0, N);
    gemm_mfma_k<128, true, true><<<rowBlocks * 4, 256, 0, stream>>>(B0, W2h, W2l, b2, B1, N);
    // --- layer 3: T = h2 @ W3, then 64-wide aggregate + b3 ---
    gemm_mfma_k<64, false, false><<<rowBlocks * 2, 256, 0, stream>>>(B1, W3h, W3l, nullptr, B0, N);
    agg64_k<<<agg64Grid, 256, 0, stream>>>(B0, offs, esrc, invd, b3, out, N);
}

// Round 8
// 305.666 us; speedup vs baseline: 1.5416x; 1.1041x over previous
//
#include <hip/hip_runtime.h>
#include <stdint.h>

// GCN: 3-layer GraphConv (norm='right'), N=50000, E=600000, 128->128->128->64.
//
// R1: hierarchical scan (scan_k 110us -> ~5us).                 [442us total]
// R3: GEMM -> MFMA split-bf16. NEUTRAL (latency-bound).
// R4: grid x4 + agg float4. gemm still 64us: TA-transaction-bound. [431us]
// R5: fragment-major W (coalesced B-frags) + bijective XCD swizzle:
//     gemm out of top-5 (<44us). agg128 now #1: 45us, 135MB L2-miss traffic
//     @3.6TB/s (h=25.6MB > 8x4MB L2; L3 absorbs).               [337us total]
// R7: FUSE agg128+gemm128 per layer: agg 64 rows -> LDS[64][132], barrier,
//     MFMA from LDS A-frags (hoisted to regs, reused over 8 col-tiles).
//     Kills B0 write+read (~51MB/layer) + 2 launches. inv_deg folded into
//     scan_final; preps merged. 11 launches (was 17).

#define N_NODES 50000
#define N_EDGES 600000
#define SCAN_CHUNK 1024

typedef __attribute__((ext_vector_type(8))) short short8v;
typedef __attribute__((ext_vector_type(4))) float f32x4;

// ---------------- CSR build ----------------

__global__ void count_deg_k(const int* __restrict__ dst, int* __restrict__ deg, int e) {
    int i = blockIdx.x * blockDim.x + threadIdx.x;
    if (i < e) atomicAdd(&deg[dst[i]], 1);
}

__global__ __launch_bounds__(256) void scan_part_k(const int* __restrict__ deg,
                                                   int* __restrict__ blockSums, int n) {
    __shared__ int red[256];
    int t = threadIdx.x;
    int base = blockIdx.x * SCAN_CHUNK + t * 4;
    int s = 0;
#pragma unroll
    for (int k = 0; k < 4; ++k) {
        int i = base + k;
        if (i < n) s += deg[i];
    }
    red[t] = s;
    __syncthreads();
    for (int off = 128; off > 0; off >>= 1) {
        if (t < off) red[t] += red[t + off];
        __syncthreads();
    }
    if (t == 0) blockSums[blockIdx.x] = red[0];
}

__global__ void scan_blocks_k(int* __restrict__ blockSums, int nb,
                              int* __restrict__ offs, int n) {
    if (threadIdx.x == 0 && blockIdx.x == 0) {
        int run = 0;
        for (int i = 0; i < nb; ++i) {
            int v = blockSums[i];
            blockSums[i] = run;
            run += v;
        }
        offs[n] = run;
    }
}

// local scan + block offset -> offs, cursor; also inv_deg (fused R7)
__global__ __launch_bounds__(256) void scan_final_k(const int* __restrict__ deg,
                                                    const int* __restrict__ blockSums,
                                                    int* __restrict__ offs,
                                                    int* __restrict__ cursor,
                                                    float* __restrict__ inv, int n) {
    __shared__ int red[256];
    int t = threadIdx.x;
    int base = blockIdx.x * SCAN_CHUNK + t * 4;
    int v[4];
    int s = 0;
#pragma unroll
    for (int k = 0; k < 4; ++k) {
        int i = base + k;
        v[k] = (i < n) ? deg[i] : 0;
        s += v[k];
    }
    red[t] = s;
    __syncthreads();
    for (int off = 1; off < 256; off <<= 1) {
        int x = (t >= off) ? red[t - off] : 0;
        __syncthreads();
        red[t] += x;
        __syncthreads();
    }
    int run = blockSums[blockIdx.x] + red[t] - s;
#pragma unroll
    for (int k = 0; k < 4; ++k) {
        int i = base + k;
        if (i < n) {
            offs[i] = run;
            cursor[i] = run;
            inv[i] = 1.0f / (float)(v[k] > 0 ? v[k] : 1);
            run += v[k];
        }
    }
}

__global__ void fill_csr_k(const int* __restrict__ src, const int* __restrict__ dst,
                           int* __restrict__ cursor, int* __restrict__ esrc, int e) {
    int i = blockIdx.x * blockDim.x + threadIdx.x;
    if (i < e) {
        int p = atomicAdd(&cursor[dst[i]], 1);
        esrc[p] = src[i];
    }
}

// ---- weight prep: W[K][NC] fp32 -> fragment-major split-bf16 hi/lo ----
// Frag idx: tile T (NC/16), kstep ks (4), lane l (64): 8 bf16 at (((T*4+ks)*64)+l)*8.
// Lane l=g*16+cl holds W[k][T*16+cl], k=ks*32+g*4+(j&3)+16*(j>>2).

__device__ __forceinline__ void prep_one(const float* __restrict__ W, short* hiF,
                                         short* loF, int NC, int idx) {
    int lane = idx & 63;
    int ks = (idx >> 6) & 3;
    int T = idx >> 8;
    int g = lane >> 4, cl = lane & 15;
    int col = T * 16 + cl;
    short8v h, l;
#pragma unroll
    for (int j = 0; j < 8; ++j) {
        int k = ks * 32 + g * 4 + (j & 3) + ((j >> 2) << 4);
        float w = W[(size_t)k * NC + col];
        unsigned u = __float_as_uint(w);
        h[j] = (short)(u >> 16);
        float res = w - __uint_as_float(u & 0xFFFF0000u);
        l[j] = (short)(__float_as_uint(res) >> 16);
    }
    ((short8v*)hiF)[idx] = h;
    ((short8v*)loF)[idx] = l;
}

__global__ void prep_all_k(const float* __restrict__ W1, const float* __restrict__ W2,
                           const float* __restrict__ W3,
                           short* W1h, short* W1l, short* W2h, short* W2l,
                           short* W3h, short* W3l) {
    int idx = blockIdx.x * 256 + threadIdx.x;
    if (idx < 2048) prep_one(W1, W1h, W1l, 128, idx);
    else if (idx < 4096) prep_one(W2, W2h, W2l, 128, idx - 2048);
    else if (idx < 5120) prep_one(W3, W3h, W3l, 64, idx - 4096);
}

// ---------------- fused agg128 + MFMA gemm (128 cols, bias+relu) ----------------
// Block = 256 thr = 4 waves = 64 dst rows. Phase 1: aggregate rows into
// LDS[64][132] (wave w: rows w*16..+15, 2 at a time, 32 lanes x float4).
// Phase 2: wave w MFMAs its 16 rows x 128 cols; A-frags hoisted (4 ks, split
// bf16 hi/lo), B from frag-major W, D += ah*bh + al*bh + ah*bl.

__global__ __launch_bounds__(256) void fused_agg_gemm_k(
    const float* __restrict__ h, const int* __restrict__ offs,
    const int* __restrict__ esrc, const float* __restrict__ inv,
    const short* __restrict__ WhF, const short* __restrict__ WlF,
    const float* __restrict__ bias, float* __restrict__ out, int n) {
    __shared__ float rows[64][132];  // +4 pad: 16B-aligned rows, de-strided banks
    int wave = threadIdx.x >> 6;
    int lane = threadIdx.x & 63;
    int rowbase = blockIdx.x * 64;

    // ---- phase 1: aggregate ----
    {
        int half = lane >> 5;   // 0/1
        int l5 = lane & 31;
        const float4* __restrict__ h4 = (const float4*)h;
        for (int rp = 0; rp < 8; ++rp) {
            int r = wave * 16 + rp * 2 + half;
            int node = rowbase + r;
            float ax = 0.f, ay = 0.f, az = 0.f, aw = 0.f;
            if (node < n) {
                int beg = offs[node], end = offs[node + 1];
                int j = beg;
                for (; j + 4 <= end; j += 4) {
                    int s0 = esrc[j], s1 = esrc[j + 1];
                    int s2 = esrc[j + 2], s3 = esrc[j + 3];
                    float4 v0 = h4[(size_t)s0 * 32 + l5];
                    float4 v1 = h4[(size_t)s1 * 32 + l5];
                    float4 v2 = h4[(size_t)s2 * 32 + l5];
                    float4 v3 = h4[(size_t)s3 * 32 + l5];
                    ax += (v0.x + v1.x) + (v2.x + v3.x);
                    ay += (v0.y + v1.y) + (v2.y + v3.y);
                    az += (v0.z + v1.z) + (v2.z + v3.z);
                    aw += (v0.w + v1.w) + (v2.w + v3.w);
                }
                for (; j < end; ++j) {
                    float4 v = h4[(size_t)esrc[j] * 32 + l5];
                    ax += v.x; ay += v.y; az += v.z; aw += v.w;
                }
                float sc = inv[node];
                ax *= sc; ay *= sc; az *= sc; aw *= sc;
            }
            float4 r4; r4.x = ax; r4.y = ay; r4.z = az; r4.w = aw;
            *(float4*)&rows[r][l5 * 4] = r4;
        }
    }
    __syncthreads();

    // ---- phase 2: MFMA ----
    int g = lane >> 4, cl = lane & 15;
    short8v ah[4], al[4];
#pragma unroll
    for (int ks = 0; ks < 4; ++ks) {
        const float* rp = &rows[wave * 16 + cl][ks * 32 + g * 4];
        float4 aL = *(const float4*)rp;
        float4 aH = *(const float4*)(rp + 16);
#define SPLIT1(J, V)                                                        \
        {                                                                   \
            unsigned u = __float_as_uint(V);                                \
            ah[ks][J] = (short)(u >> 16);                                   \
            float res = (V) - __uint_as_float(u & 0xFFFF0000u);             \
            al[ks][J] = (short)(__float_as_uint(res) >> 16);                \
        }
        SPLIT1(0, aL.x) SPLIT1(1, aL.y) SPLIT1(2, aL.z) SPLIT1(3, aL.w)
        SPLIT1(4, aH.x) SPLIT1(5, aH.y) SPLIT1(6, aH.z) SPLIT1(7, aH.w)
#undef SPLIT1
    }

#pragma unroll
    for (int t = 0; t < 8; ++t) {
        f32x4 acc = {0.f, 0.f, 0.f, 0.f};
#pragma unroll
        for (int ks = 0; ks < 4; ++ks) {
            size_t fo = ((size_t)(t * 4 + ks) * 64 + lane) * 8;
            short8v bh = *(const short8v*)(WhF + fo);
            short8v bl = *(const short8v*)(WlF + fo);
            acc = __builtin_amdgcn_mfma_f32_16x16x32_bf16(ah[ks], bh, acc, 0, 0, 0);
            acc = __builtin_amdgcn_mfma_f32_16x16x32_bf16(al[ks], bh, acc, 0, 0, 0);
            acc = __builtin_amdgcn_mfma_f32_16x16x32_bf16(ah[ks], bl, acc, 0, 0, 0);
        }
        int col = t * 16 + cl;
        float bv = bias[col];
#pragma unroll
        for (int r = 0; r < 4; ++r) {
            int gr = rowbase + wave * 16 + g * 4 + r;
            if (gr < n) {
                float v = fmaxf(acc[r] + bv, 0.f);
                out[(size_t)gr * 128 + col] = v;
            }
        }
    }
}

// ---------------- agg64: 4 nodes/wave, float4/lane, fused bias, final out ------

__global__ __launch_bounds__(256) void agg64_k(const float* __restrict__ t64,
                                               const int* __restrict__ offs,
                                               const int* __restrict__ esrc,
                                               const float* __restrict__ inv,
                                               const float* __restrict__ bias,
                                               float* __restrict__ out, int n) {
    int gt = blockIdx.x * 256 + threadIdx.x;
    int wv = gt >> 6;
    int q = (threadIdx.x >> 4) & 3;
    int l4 = threadIdx.x & 15;
    int node = wv * 4 + q;
    if (node >= n) return;
    int beg = offs[node], end = offs[node + 1];
    const float4* __restrict__ h4 = (const float4*)t64;
    float4 a = {0.f, 0.f, 0.f, 0.f};
    int j = beg;
    for (; j + 4 <= end; j += 4) {
        int s0 = esrc[j], s1 = esrc[j + 1], s2 = esrc[j + 2], s3 = esrc[j + 3];
        float4 v0 = h4[(size_t)s0 * 16 + l4];
        float4 v1 = h4[(size_t)s1 * 16 + l4];
        float4 v2 = h4[(size_t)s2 * 16 + l4];
        float4 v3 = h4[(size_t)s3 * 16 + l4];
        a.x += (v0.x + v1.x) + (v2.x + v3.x);
        a.y += (v0.y + v1.y) + (v2.y + v3.y);
        a.z += (v0.z + v1.z) + (v2.z + v3.z);
        a.w += (v0.w + v1.w) + (v2.w + v3.w);
    }
    for (; j < end; ++j) {
        float4 v = h4[(size_t)esrc[j] * 16 + l4];
        a.x += v.x; a.y += v.y; a.z += v.z; a.w += v.w;
    }
    float sc = inv[node];
    float4 b = ((const float4*)bias)[l4];
    float4 r;
    r.x = a.x * sc + b.x; r.y = a.y * sc + b.y;
    r.z = a.z * sc + b.z; r.w = a.w * sc + b.w;
    ((float4*)out)[(size_t)node * 16 + l4] = r;
}

// ---------------- MFMA GEMM (layer-3: [M,128] x W3 -> [M,64], no bias) --------

template <int NCTOT, bool HASB, bool RELU>
__global__ __launch_bounds__(256) void gemm_mfma_k(const float* __restrict__ A,
                                                   const short* __restrict__ WhF,
                                                   const short* __restrict__ WlF,
                                                   const float* __restrict__ bias,
                                                   float* __restrict__ out, int M) {
    constexpr int CT = NCTOT / 32;
    int nwg = gridDim.x;
    int b = blockIdx.x;
    int qq = nwg >> 3, rr = nwg & 7;
    int xcd = b & 7, ix = b >> 3;
    int sw = (xcd < rr ? xcd * (qq + 1) : rr * (qq + 1) + (xcd - rr) * qq) + ix;
    int rowblk = sw / CT;
    int colblk = sw % CT;

    int wave = threadIdx.x >> 6;
    int lane = threadIdx.x & 63;
    int g = lane >> 4;
    int cl = lane & 15;
    int rowbase = rowblk * 64 + wave * 16;
    int arow = rowbase + cl;
    if (arow >= M) arow = M - 1;
    const float* arowp = A + (size_t)arow * 128;

    f32x4 acc0 = {0.f, 0.f, 0.f, 0.f}, acc1 = {0.f, 0.f, 0.f, 0.f};

#pragma unroll
    for (int ks = 0; ks < 4; ++ks) {
        int k0 = ks * 32 + g * 4;
        float4 aL = *(const float4*)(arowp + k0);
        float4 aH = *(const float4*)(arowp + k0 + 16);
        short8v ah, al;
        {
#define SPLIT1(J, V)                                                        \
            {                                                               \
                unsigned u = __float_as_uint(V);                            \
                ah[J] = (short)(u >> 16);                                   \
                float res = (V) - __uint_as_float(u & 0xFFFF0000u);         \
                al[J] = (short)(__float_as_uint(res) >> 16);                \
            }
            SPLIT1(0, aL.x) SPLIT1(1, aL.y) SPLIT1(2, aL.z) SPLIT1(3, aL.w)
            SPLIT1(4, aH.x) SPLIT1(5, aH.y) SPLIT1(6, aH.z) SPLIT1(7, aH.w)
#undef SPLIT1
        }
#pragma unroll
        for (int t = 0; t < 2; ++t) {
            int tileIdx = colblk * 2 + t;
            size_t fo = ((size_t)(tileIdx * 4 + ks) * 64 + lane) * 8;
            short8v bh = *(const short8v*)(WhF + fo);
            short8v bl = *(const short8v*)(WlF + fo);
            f32x4 acc = (t == 0) ? acc0 : acc1;
            acc = __builtin_amdgcn_mfma_f32_16x16x32_bf16(ah, bh, acc, 0, 0, 0);
            acc = __builtin_amdgcn_mfma_f32_16x16x32_bf16(al, bh, acc, 0, 0, 0);
            acc = __builtin_amdgcn_mfma_f32_16x16x32_bf16(ah, bl, acc, 0, 0, 0);
            if (t == 0) acc0 = acc; else acc1 = acc;
        }
    }

#pragma unroll
    for (int t = 0; t < 2; ++t) {
        f32x4 acc = (t == 0) ? acc0 : acc1;
        int col = colblk * 32 + t * 16 + cl;
        float bv = 0.f;
        if (HASB) bv = bias[col];
#pragma unroll
        for (int r = 0; r < 4; ++r) {
            int gr = rowbase + g * 4 + r;
            if (gr < M) {
                float v = acc[r] + bv;
                if (RELU) v = fmaxf(v, 0.f);
                out[(size_t)gr * NCTOT + col] = v;
            }
        }
    }
}

// ---------------- launch ----------------

extern "C" void kernel_launch(void* const* d_in, const int* in_sizes, int n_in,
                              void* d_out, int out_size, void* d_ws, size_t ws_size,
                              hipStream_t stream) {
    const int N = N_NODES, E = N_EDGES;
    const float* feat = (const float*)d_in[0];
    const int* src = (const int*)d_in[1];
    const int* dst = (const int*)d_in[2];
    const float* W1 = (const float*)d_in[3];
    const float* b1 = (const float*)d_in[4];
    const float* W2 = (const float*)d_in[5];
    const float* b2 = (const float*)d_in[6];
    const float* W3 = (const float*)d_in[7];
    const float* b3 = (const float*)d_in[8];
    float* out = (float*)d_out;

    const int nScanBlocks = (N + SCAN_CHUNK - 1) / SCAN_CHUNK;  // 49

    // workspace layout
    float* B0 = (float*)d_ws;                       // N*128 f32
    float* B1 = B0 + (size_t)N * 128;               // N*128 f32
    int* deg = (int*)(B1 + (size_t)N * 128);        // N
    float* invd = (float*)(deg + N);                // N
    int* offs = (int*)(invd + N);                   // N+2 (pad -> cursor 8B-aligned)
    int* cursor = offs + N + 2;                     // N
    int* esrc = cursor + N;                         // E
    int* blockSums = esrc + E;                      // nScanBlocks
    // WF buffers alias `cursor` (dead after fill_csr_k): 160KB <= N*4B
    short* W1h = (short*)cursor;
    short* W1l = W1h + 16384;
    short* W2h = W1l + 16384;
    short* W2l = W2h + 16384;
    short* W3h = W2l + 16384;
    short* W3l = W3h + 8192;

    // --- CSR build ---
    hipMemsetAsync(deg, 0, (size_t)N * sizeof(int), stream);
    count_deg_k<<<(E + 255) / 256, 256, 0, stream>>>(dst, deg, E);
    scan_part_k<<<nScanBlocks, 256, 0, stream>>>(deg, blockSums, N);
    scan_blocks_k<<<1, 64, 0, stream>>>(blockSums, nScanBlocks, offs, N);
    scan_final_k<<<nScanBlocks, 256, 0, stream>>>(deg, blockSums, offs, cursor, invd, N);
    fill_csr_k<<<(E + 255) / 256, 256, 0, stream>>>(src, dst, cursor, esrc, E);

    // --- weight prep (after fill_csr: WF aliases cursor) ---
    prep_all_k<<<20, 256, 0, stream>>>(W1, W2, W3, W1h, W1l, W2h, W2l, W3h, W3l);

    const int fusedGrid = (N + 63) / 64;     // 782
    const int agg64Grid = (N + 15) / 16;
    const int rowBlocks = (N + 63) / 64;

    // --- layer 1: fused agg+gemm (feat -> B1) ---
    fused_agg_gemm_k<<<fusedGrid, 256, 0, stream>>>(feat, offs, esrc, invd,
                                                    W1h, W1l, b1, B1, N);
    // --- layer 2: fused agg+gemm (B1 -> B0) ---
    fused_agg_gemm_k<<<fusedGrid, 256, 0, stream>>>(B1, offs, esrc, invd,
                                                    W2h, W2l, b2, B0, N);
    // --- layer 3: T = B0 @ W3 -> B1, then agg64 + b3 -> out ---
    gemm_mfma_k<64, false, false><<<rowBlocks * 2, 256, 0, stream>>>(B0, W3h, W3l,
                                                                     nullptr, B1, N);
    agg64_k<<<agg64Grid, 256, 0, stream>>>(B1, offs, esrc, invd, b3, out, N);
}

// Round 9
// 291.680 us; speedup vs baseline: 1.6155x; 1.0480x over previous
//
#include <hip/hip_runtime.h>
#include <stdint.h>

// GCN: 3-layer GraphConv (norm='right'), N=50000, E=600000, 128->128->128->64.
//
// R1: hierarchical scan (scan_k 110us -> ~5us).                 [442us total]
// R3: GEMM -> MFMA split-bf16. NEUTRAL (latency-bound).
// R4: grid x4 + agg float4. gemm still 64us: TA-transaction-bound. [431us]
// R5: fragment-major W (coalesced B-frags) + XCD swizzle. gemm <44us;
//     agg128 #1 (45us, 135MB L2-miss @3.6TB/s).                 [337us total]
// R7: fused agg128+gemm128 (LDS[64][132] + MFMA). 60us/layer but occupancy
//     28% (grid 782 = 3 blk/CU) -> gather path at 2.6TB/s.      [305us total]
// R8: occupancy fix: 32 rows/block (grid 1563 = 6.1 blk/CU), 256 thr,
//     launch_bounds(256,6); ks-outer MFMA loop (1 A-frag live, acc[4]).

#define N_NODES 50000
#define N_EDGES 600000
#define SCAN_CHUNK 1024

typedef __attribute__((ext_vector_type(8))) short short8v;
typedef __attribute__((ext_vector_type(4))) float f32x4;

// ---------------- CSR build ----------------

__global__ void count_deg_k(const int* __restrict__ dst, int* __restrict__ deg, int e) {
    int i = blockIdx.x * blockDim.x + threadIdx.x;
    if (i < e) atomicAdd(&deg[dst[i]], 1);
}

__global__ __launch_bounds__(256) void scan_part_k(const int* __restrict__ deg,
                                                   int* __restrict__ blockSums, int n) {
    __shared__ int red[256];
    int t = threadIdx.x;
    int base = blockIdx.x * SCAN_CHUNK + t * 4;
    int s = 0;
#pragma unroll
    for (int k = 0; k < 4; ++k) {
        int i = base + k;
        if (i < n) s += deg[i];
    }
    red[t] = s;
    __syncthreads();
    for (int off = 128; off > 0; off >>= 1) {
        if (t < off) red[t] += red[t + off];
        __syncthreads();
    }
    if (t == 0) blockSums[blockIdx.x] = red[0];
}

__global__ void scan_blocks_k(int* __restrict__ blockSums, int nb,
                              int* __restrict__ offs, int n) {
    if (threadIdx.x == 0 && blockIdx.x == 0) {
        int run = 0;
        for (int i = 0; i < nb; ++i) {
            int v = blockSums[i];
            blockSums[i] = run;
            run += v;
        }
        offs[n] = run;
    }
}

// local scan + block offset -> offs, cursor; also inv_deg
__global__ __launch_bounds__(256) void scan_final_k(const int* __restrict__ deg,
                                                    const int* __restrict__ blockSums,
                                                    int* __restrict__ offs,
                                                    int* __restrict__ cursor,
                                                    float* __restrict__ inv, int n) {
    __shared__ int red[256];
    int t = threadIdx.x;
    int base = blockIdx.x * SCAN_CHUNK + t * 4;
    int v[4];
    int s = 0;
#pragma unroll
    for (int k = 0; k < 4; ++k) {
        int i = base + k;
        v[k] = (i < n) ? deg[i] : 0;
        s += v[k];
    }
    red[t] = s;
    __syncthreads();
    for (int off = 1; off < 256; off <<= 1) {
        int x = (t >= off) ? red[t - off] : 0;
        __syncthreads();
        red[t] += x;
        __syncthreads();
    }
    int run = blockSums[blockIdx.x] + red[t] - s;
#pragma unroll
    for (int k = 0; k < 4; ++k) {
        int i = base + k;
        if (i < n) {
            offs[i] = run;
            cursor[i] = run;
            inv[i] = 1.0f / (float)(v[k] > 0 ? v[k] : 1);
            run += v[k];
        }
    }
}

__global__ void fill_csr_k(const int* __restrict__ src, const int* __restrict__ dst,
                           int* __restrict__ cursor, int* __restrict__ esrc, int e) {
    int i = blockIdx.x * blockDim.x + threadIdx.x;
    if (i < e) {
        int p = atomicAdd(&cursor[dst[i]], 1);
        esrc[p] = src[i];
    }
}

// ---- weight prep: W[K][NC] fp32 -> fragment-major split-bf16 hi/lo ----
// Frag idx: tile T (NC/16), kstep ks (4), lane l (64): 8 bf16 at (((T*4+ks)*64)+l)*8.
// Lane l=g*16+cl holds W[k][T*16+cl], k=ks*32+g*4+(j&3)+16*(j>>2).

__device__ __forceinline__ void prep_one(const float* __restrict__ W, short* hiF,
                                         short* loF, int NC, int idx) {
    int lane = idx & 63;
    int ks = (idx >> 6) & 3;
    int T = idx >> 8;
    int g = lane >> 4, cl = lane & 15;
    int col = T * 16 + cl;
    short8v h, l;
#pragma unroll
    for (int j = 0; j < 8; ++j) {
        int k = ks * 32 + g * 4 + (j & 3) + ((j >> 2) << 4);
        float w = W[(size_t)k * NC + col];
        unsigned u = __float_as_uint(w);
        h[j] = (short)(u >> 16);
        float res = w - __uint_as_float(u & 0xFFFF0000u);
        l[j] = (short)(__float_as_uint(res) >> 16);
    }
    ((short8v*)hiF)[idx] = h;
    ((short8v*)loF)[idx] = l;
}

__global__ void prep_all_k(const float* __restrict__ W1, const float* __restrict__ W2,
                           const float* __restrict__ W3,
                           short* W1h, short* W1l, short* W2h, short* W2l,
                           short* W3h, short* W3l) {
    int idx = blockIdx.x * 256 + threadIdx.x;
    if (idx < 2048) prep_one(W1, W1h, W1l, 128, idx);
    else if (idx < 4096) prep_one(W2, W2h, W2l, 128, idx - 2048);
    else if (idx < 5120) prep_one(W3, W3h, W3l, 64, idx - 4096);
}

// ---------------- fused agg128 + MFMA gemm (128 cols, bias+relu) ----------------
// Block = 256 thr = 4 waves = 32 dst rows (grid 1563 ~= 6.1 blk/CU).
// Phase 1: wave w aggregates rows [w*8, w*8+8), 2 nodes at a time (32 lanes x
// float4 each) -> LDS[32][132].
// Phase 2: wave w owns rows (w&1)*16..+16, cols (w>>1)*64..+64. ks-outer loop:
// one A-frag (split hi/lo) live; inner 4 col-tiles: B frag-major, 3 MFMA each.

__global__ __launch_bounds__(256, 6) void fused_agg_gemm_k(
    const float* __restrict__ h, const int* __restrict__ offs,
    const int* __restrict__ esrc, const float* __restrict__ inv,
    const short* __restrict__ WhF, const short* __restrict__ WlF,
    const float* __restrict__ bias, float* __restrict__ out, int n) {
    __shared__ float rows[32][132];  // +4 pad
    int wave = threadIdx.x >> 6;
    int lane = threadIdx.x & 63;
    int rowbase = blockIdx.x * 32;

    // ---- phase 1: aggregate 8 rows per wave ----
    {
        int half = lane >> 5;   // 0/1
        int l5 = lane & 31;
        const float4* __restrict__ h4 = (const float4*)h;
#pragma unroll
        for (int rp = 0; rp < 4; ++rp) {
            int r = wave * 8 + rp * 2 + half;
            int node = rowbase + r;
            float ax = 0.f, ay = 0.f, az = 0.f, aw = 0.f;
            if (node < n) {
                int beg = offs[node], end = offs[node + 1];
                int j = beg;
                for (; j + 4 <= end; j += 4) {
                    int s0 = esrc[j], s1 = esrc[j + 1];
                    int s2 = esrc[j + 2], s3 = esrc[j + 3];
                    float4 v0 = h4[(size_t)s0 * 32 + l5];
                    float4 v1 = h4[(size_t)s1 * 32 + l5];
                    float4 v2 = h4[(size_t)s2 * 32 + l5];
                    float4 v3 = h4[(size_t)s3 * 32 + l5];
                    ax += (v0.x + v1.x) + (v2.x + v3.x);
                    ay += (v0.y + v1.y) + (v2.y + v3.y);
                    az += (v0.z + v1.z) + (v2.z + v3.z);
                    aw += (v0.w + v1.w) + (v2.w + v3.w);
                }
                for (; j < end; ++j) {
                    float4 v = h4[(size_t)esrc[j] * 32 + l5];
                    ax += v.x; ay += v.y; az += v.z; aw += v.w;
                }
                float sc = inv[node];
                ax *= sc; ay *= sc; az *= sc; aw *= sc;
            }
            float4 r4; r4.x = ax; r4.y = ay; r4.z = az; r4.w = aw;
            *(float4*)&rows[r][l5 * 4] = r4;
        }
    }
    __syncthreads();

    // ---- phase 2: MFMA (16 rows x 64 cols per wave) ----
    int g = lane >> 4, cl = lane & 15;
    int rowtile = wave & 1;          // 0/1: which 16 rows
    int colhalf = wave >> 1;         // 0/1: which 64 cols
    f32x4 acc[4];
#pragma unroll
    for (int t = 0; t < 4; ++t) acc[t] = (f32x4){0.f, 0.f, 0.f, 0.f};

#pragma unroll
    for (int ks = 0; ks < 4; ++ks) {
        const float* rp = &rows[rowtile * 16 + cl][ks * 32 + g * 4];
        float4 aL = *(const float4*)rp;
        float4 aH = *(const float4*)(rp + 16);
        short8v ah, al;
#define SPLIT1(J, V)                                                        \
        {                                                                   \
            unsigned u = __float_as_uint(V);                                \
            ah[J] = (short)(u >> 16);                                       \
            float res = (V) - __uint_as_float(u & 0xFFFF0000u);             \
            al[J] = (short)(__float_as_uint(res) >> 16);                    \
        }
        SPLIT1(0, aL.x) SPLIT1(1, aL.y) SPLIT1(2, aL.z) SPLIT1(3, aL.w)
        SPLIT1(4, aH.x) SPLIT1(5, aH.y) SPLIT1(6, aH.z) SPLIT1(7, aH.w)
#undef SPLIT1
#pragma unroll
        for (int t = 0; t < 4; ++t) {
            int tileIdx = colhalf * 4 + t;
            size_t fo = ((size_t)(tileIdx * 4 + ks) * 64 + lane) * 8;
            short8v bh = *(const short8v*)(WhF + fo);
            short8v bl = *(const short8v*)(WlF + fo);
            acc[t] = __builtin_amdgcn_mfma_f32_16x16x32_bf16(ah, bh, acc[t], 0, 0, 0);
            acc[t] = __builtin_amdgcn_mfma_f32_16x16x32_bf16(al, bh, acc[t], 0, 0, 0);
            acc[t] = __builtin_amdgcn_mfma_f32_16x16x32_bf16(ah, bl, acc[t], 0, 0, 0);
        }
    }

#pragma unroll
    for (int t = 0; t < 4; ++t) {
        int col = (colhalf * 4 + t) * 16 + cl;
        float bv = bias[col];
#pragma unroll
        for (int r = 0; r < 4; ++r) {
            int gr = rowbase + rowtile * 16 + g * 4 + r;
            if (gr < n) {
                float v = fmaxf(acc[t][r] + bv, 0.f);
                out[(size_t)gr * 128 + col] = v;
            }
        }
    }
}

// ---------------- agg64: 4 nodes/wave, float4/lane, fused bias, final out ------

__global__ __launch_bounds__(256) void agg64_k(const float* __restrict__ t64,
                                               const int* __restrict__ offs,
                                               const int* __restrict__ esrc,
                                               const float* __restrict__ inv,
                                               const float* __restrict__ bias,
                                               float* __restrict__ out, int n) {
    int gt = blockIdx.x * 256 + threadIdx.x;
    int wv = gt >> 6;
    int q = (threadIdx.x >> 4) & 3;
    int l4 = threadIdx.x & 15;
    int node = wv * 4 + q;
    if (node >= n) return;
    int beg = offs[node], end = offs[node + 1];
    const float4* __restrict__ h4 = (const float4*)t64;
    float4 a = {0.f, 0.f, 0.f, 0.f};
    int j = beg;
    for (; j + 4 <= end; j += 4) {
        int s0 = esrc[j], s1 = esrc[j + 1], s2 = esrc[j + 2], s3 = esrc[j + 3];
        float4 v0 = h4[(size_t)s0 * 16 + l4];
        float4 v1 = h4[(size_t)s1 * 16 + l4];
        float4 v2 = h4[(size_t)s2 * 16 + l4];
        float4 v3 = h4[(size_t)s3 * 16 + l4];
        a.x += (v0.x + v1.x) + (v2.x + v3.x);
        a.y += (v0.y + v1.y) + (v2.y + v3.y);
        a.z += (v0.z + v1.z) + (v2.z + v3.z);
        a.w += (v0.w + v1.w) + (v2.w + v3.w);
    }
    for (; j < end; ++j) {
        float4 v = h4[(size_t)esrc[j] * 16 + l4];
        a.x += v.x; a.y += v.y; a.z += v.z; a.w += v.w;
    }
    float sc = inv[node];
    float4 b = ((const float4*)bias)[l4];
    float4 r;
    r.x = a.x * sc + b.x; r.y = a.y * sc + b.y;
    r.z = a.z * sc + b.z; r.w = a.w * sc + b.w;
    ((float4*)out)[(size_t)node * 16 + l4] = r;
}

// ---------------- MFMA GEMM (layer-3: [M,128] x W3 -> [M,64], no bias) --------

template <int NCTOT, bool HASB, bool RELU>
__global__ __launch_bounds__(256) void gemm_mfma_k(const float* __restrict__ A,
                                                   const short* __restrict__ WhF,
                                                   const short* __restrict__ WlF,
                                                   const float* __restrict__ bias,
                                                   float* __restrict__ out, int M) {
    constexpr int CT = NCTOT / 32;
    int nwg = gridDim.x;
    int b = blockIdx.x;
    int qq = nwg >> 3, rr = nwg & 7;
    int xcd = b & 7, ix = b >> 3;
    int sw = (xcd < rr ? xcd * (qq + 1) : rr * (qq + 1) + (xcd - rr) * qq) + ix;
    int rowblk = sw / CT;
    int colblk = sw % CT;

    int wave = threadIdx.x >> 6;
    int lane = threadIdx.x & 63;
    int g = lane >> 4;
    int cl = lane & 15;
    int rowbase = rowblk * 64 + wave * 16;
    int arow = rowbase + cl;
    if (arow >= M) arow = M - 1;
    const float* arowp = A + (size_t)arow * 128;

    f32x4 acc0 = {0.f, 0.f, 0.f, 0.f}, acc1 = {0.f, 0.f, 0.f, 0.f};

#pragma unroll
    for (int ks = 0; ks < 4; ++ks) {
        int k0 = ks * 32 + g * 4;
        float4 aL = *(const float4*)(arowp + k0);
        float4 aH = *(const float4*)(arowp + k0 + 16);
        short8v ah, al;
        {
#define SPLIT1(J, V)                                                        \
            {                                                               \
                unsigned u = __float_as_uint(V);                            \
                ah[J] = (short)(u >> 16);                                   \
                float res = (V) - __uint_as_float(u & 0xFFFF0000u);         \
                al[J] = (short)(__float_as_uint(res) >> 16);                \
            }
            SPLIT1(0, aL.x) SPLIT1(1, aL.y) SPLIT1(2, aL.z) SPLIT1(3, aL.w)
            SPLIT1(4, aH.x) SPLIT1(5, aH.y) SPLIT1(6, aH.z) SPLIT1(7, aH.w)
#undef SPLIT1
        }
#pragma unroll
        for (int t = 0; t < 2; ++t) {
            int tileIdx = colblk * 2 + t;
            size_t fo = ((size_t)(tileIdx * 4 + ks) * 64 + lane) * 8;
            short8v bh = *(const short8v*)(WhF + fo);
            short8v bl = *(const short8v*)(WlF + fo);
            f32x4 acc = (t == 0) ? acc0 : acc1;
            acc = __builtin_amdgcn_mfma_f32_16x16x32_bf16(ah, bh, acc, 0, 0, 0);
            acc = __builtin_amdgcn_mfma_f32_16x16x32_bf16(al, bh, acc, 0, 0, 0);
            acc = __builtin_amdgcn_mfma_f32_16x16x32_bf16(ah, bl, acc, 0, 0, 0);
            if (t == 0) acc0 = acc; else acc1 = acc;
        }
    }

#pragma unroll
    for (int t = 0; t < 2; ++t) {
        f32x4 acc = (t == 0) ? acc0 : acc1;
        int col = colblk * 32 + t * 16 + cl;
        float bv = 0.f;
        if (HASB) bv = bias[col];
#pragma unroll
        for (int r = 0; r < 4; ++r) {
            int gr = rowbase + g * 4 + r;
            if (gr < M) {
                float v = acc[r] + bv;
                if (RELU) v = fmaxf(v, 0.f);
                out[(size_t)gr * NCTOT + col] = v;
            }
        }
    }
}

// ---------------- launch ----------------

extern "C" void kernel_launch(void* const* d_in, const int* in_sizes, int n_in,
                              void* d_out, int out_size, void* d_ws, size_t ws_size,
                              hipStream_t stream) {
    const int N = N_NODES, E = N_EDGES;
    const float* feat = (const float*)d_in[0];
    const int* src = (const int*)d_in[1];
    const int* dst = (const int*)d_in[2];
    const float* W1 = (const float*)d_in[3];
    const float* b1 = (const float*)d_in[4];
    const float* W2 = (const float*)d_in[5];
    const float* b2 = (const float*)d_in[6];
    const float* W3 = (const float*)d_in[7];
    const float* b3 = (const float*)d_in[8];
    float* out = (float*)d_out;

    const int nScanBlocks = (N + SCAN_CHUNK - 1) / SCAN_CHUNK;  // 49

    // workspace layout
    float* B0 = (float*)d_ws;                       // N*128 f32
    float* B1 = B0 + (size_t)N * 128;               // N*128 f32
    int* deg = (int*)(B1 + (size_t)N * 128);        // N
    float* invd = (float*)(deg + N);                // N
    int* offs = (int*)(invd + N);                   // N+2 (pad -> cursor 8B-aligned)
    int* cursor = offs + N + 2;                     // N
    int* esrc = cursor + N;                         // E
    int* blockSums = esrc + E;                      // nScanBlocks
    // WF buffers alias `cursor` (dead after fill_csr_k): 160KB <= N*4B
    short* W1h = (short*)cursor;
    short* W1l = W1h + 16384;
    short* W2h = W1l + 16384;
    short* W2l = W2h + 16384;
    short* W3h = W2l + 16384;
    short* W3l = W3h + 8192;

    // --- CSR build ---
    hipMemsetAsync(deg, 0, (size_t)N * sizeof(int), stream);
    count_deg_k<<<(E + 255) / 256, 256, 0, stream>>>(dst, deg, E);
    scan_part_k<<<nScanBlocks, 256, 0, stream>>>(deg, blockSums, N);
    scan_blocks_k<<<1, 64, 0, stream>>>(blockSums, nScanBlocks, offs, N);
    scan_final_k<<<nScanBlocks, 256, 0, stream>>>(deg, blockSums, offs, cursor, invd, N);
    fill_csr_k<<<(E + 255) / 256, 256, 0, stream>>>(src, dst, cursor, esrc, E);

    // --- weight prep (after fill_csr: WF aliases cursor) ---
    prep_all_k<<<20, 256, 0, stream>>>(W1, W2, W3, W1h, W1l, W2h, W2l, W3h, W3l);

    const int fusedGrid = (N + 31) / 32;     // 1563
    const int agg64Grid = (N + 15) / 16;
    const int rowBlocks = (N + 63) / 64;

    // --- layer 1: fused agg+gemm (feat -> B1) ---
    fused_agg_gemm_k<<<fusedGrid, 256, 0, stream>>>(feat, offs, esrc, invd,
                                                    W1h, W1l, b1, B1, N);
    // --- layer 2: fused agg+gemm (B1 -> B0) ---
    fused_agg_gemm_k<<<fusedGrid, 256, 0, stream>>>(B1, offs, esrc, invd,
                                                    W2h, W2l, b2, B0, N);
    // --- layer 3: T = B0 @ W3 -> B1, then agg64 + b3 -> out ---
    gemm_mfma_k<64, false, false><<<rowBlocks * 2, 256, 0, stream>>>(B0, W3h, W3l,
                                                                     nullptr, B1, N);
    agg64_k<<<agg64Grid, 256, 0, stream>>>(B1, offs, esrc, invd, b3, out, N);
}

// Round 10
// 281.000 us; speedup vs baseline: 1.6769x; 1.0380x over previous
//
#include <hip/hip_runtime.h>
#include <stdint.h>

// GCN: 3-layer GraphConv (norm='right'), N=50000, E=600000, 128->128->128->64.
//
// R1: hierarchical scan (110us -> ~5us).                        [442us]
// R3: MFMA split-bf16 GEMM. NEUTRAL (latency-bound).
// R4: grid x4 + agg float4 -> TA-transaction diagnosis.         [431us]
// R5: fragment-major W + XCD swizzle: gemm off top-5.           [337us]
// R7: fused agg128+gemm128 (LDS + MFMA).                        [305us]
// R8: 32 rows/block: occ 28->53%, gather 2.6->3.05 TB/s.        [292us]
// R9: (a) 16 rows/block, grid 3125 (12.2 blk/CU, bounds(256,6) -> 75% occ
//     ceiling, 2x oversubscription for ramp/tail); (b) W3TAIL: layer-3 GEMM
//     fused into layer-2 kernel (h2 stays in LDS; write only T N*64),
//     standalone gemm64 deleted.

#define N_NODES 50000
#define N_EDGES 600000
#define SCAN_CHUNK 1024

typedef __attribute__((ext_vector_type(8))) short short8v;
typedef __attribute__((ext_vector_type(4))) float f32x4;

// ---------------- CSR build ----------------

__global__ void count_deg_k(const int* __restrict__ dst, int* __restrict__ deg, int e) {
    int i = blockIdx.x * blockDim.x + threadIdx.x;
    if (i < e) atomicAdd(&deg[dst[i]], 1);
}

__global__ __launch_bounds__(256) void scan_part_k(const int* __restrict__ deg,
                                                   int* __restrict__ blockSums, int n) {
    __shared__ int red[256];
    int t = threadIdx.x;
    int base = blockIdx.x * SCAN_CHUNK + t * 4;
    int s = 0;
#pragma unroll
    for (int k = 0; k < 4; ++k) {
        int i = base + k;
        if (i < n) s += deg[i];
    }
    red[t] = s;
    __syncthreads();
    for (int off = 128; off > 0; off >>= 1) {
        if (t < off) red[t] += red[t + off];
        __syncthreads();
    }
    if (t == 0) blockSums[blockIdx.x] = red[0];
}

__global__ void scan_blocks_k(int* __restrict__ blockSums, int nb,
                              int* __restrict__ offs, int n) {
    if (threadIdx.x == 0 && blockIdx.x == 0) {
        int run = 0;
        for (int i = 0; i < nb; ++i) {
            int v = blockSums[i];
            blockSums[i] = run;
            run += v;
        }
        offs[n] = run;
    }
}

__global__ __launch_bounds__(256) void scan_final_k(const int* __restrict__ deg,
                                                    const int* __restrict__ blockSums,
                                                    int* __restrict__ offs,
                                                    int* __restrict__ cursor,
                                                    float* __restrict__ inv, int n) {
    __shared__ int red[256];
    int t = threadIdx.x;
    int base = blockIdx.x * SCAN_CHUNK + t * 4;
    int v[4];
    int s = 0;
#pragma unroll
    for (int k = 0; k < 4; ++k) {
        int i = base + k;
        v[k] = (i < n) ? deg[i] : 0;
        s += v[k];
    }
    red[t] = s;
    __syncthreads();
    for (int off = 1; off < 256; off <<= 1) {
        int x = (t >= off) ? red[t - off] : 0;
        __syncthreads();
        red[t] += x;
        __syncthreads();
    }
    int run = blockSums[blockIdx.x] + red[t] - s;
#pragma unroll
    for (int k = 0; k < 4; ++k) {
        int i = base + k;
        if (i < n) {
            offs[i] = run;
            cursor[i] = run;
            inv[i] = 1.0f / (float)(v[k] > 0 ? v[k] : 1);
            run += v[k];
        }
    }
}

__global__ void fill_csr_k(const int* __restrict__ src, const int* __restrict__ dst,
                           int* __restrict__ cursor, int* __restrict__ esrc, int e) {
    int i = blockIdx.x * blockDim.x + threadIdx.x;
    if (i < e) {
        int p = atomicAdd(&cursor[dst[i]], 1);
        esrc[p] = src[i];
    }
}

// ---- weight prep: W[K][NC] fp32 -> fragment-major split-bf16 hi/lo ----
// Frag idx: tile T (NC/16), kstep ks (4), lane l (64): 8 bf16 at (((T*4+ks)*64)+l)*8.
// Lane l=g*16+cl holds W[k][T*16+cl], k=ks*32+g*4+(j&3)+16*(j>>2).

__device__ __forceinline__ void prep_one(const float* __restrict__ W, short* hiF,
                                         short* loF, int NC, int idx) {
    int lane = idx & 63;
    int ks = (idx >> 6) & 3;
    int T = idx >> 8;
    int g = lane >> 4, cl = lane & 15;
    int col = T * 16 + cl;
    short8v h, l;
#pragma unroll
    for (int j = 0; j < 8; ++j) {
        int k = ks * 32 + g * 4 + (j & 3) + ((j >> 2) << 4);
        float w = W[(size_t)k * NC + col];
        unsigned u = __float_as_uint(w);
        h[j] = (short)(u >> 16);
        float res = w - __uint_as_float(u & 0xFFFF0000u);
        l[j] = (short)(__float_as_uint(res) >> 16);
    }
    ((short8v*)hiF)[idx] = h;
    ((short8v*)loF)[idx] = l;
}

__global__ void prep_all_k(const float* __restrict__ W1, const float* __restrict__ W2,
                           const float* __restrict__ W3,
                           short* W1h, short* W1l, short* W2h, short* W2l,
                           short* W3h, short* W3l) {
    int idx = blockIdx.x * 256 + threadIdx.x;
    if (idx < 2048) prep_one(W1, W1h, W1l, 128, idx);
    else if (idx < 4096) prep_one(W2, W2h, W2l, 128, idx - 2048);
    else if (idx < 5120) prep_one(W3, W3h, W3l, 64, idx - 4096);
}

// ---------------- fused agg + gemm (+ optional W3 tail) ----------------
// Block = 256 thr = 4 waves = 16 dst rows (grid 3125 = 12.2 blk/CU; bounds
// (256,6) -> 6 blk/CU resident, 2x oversubscribed for ramp/tail).
// Phase 1: wave w aggregates rows [w*4,w*4+4), 2 nodes at a time (half-wave
// x float4) -> LDS rows[16][132].
// Phase 2: all waves share the 16 rows; wave w owns cols w*32..+32 (2 tiles).
//   A-frags hoisted (4 ks, split hi/lo), barrier (frees LDS), MFMA, bias+relu.
//   W3TAIL=0: write h2 16x128 to out.
//   W3TAIL=1: write h2 into LDS, barrier, phase 3: wave w = col-tile w of W3
//   (16 cols): A-frags from h2, 12 MFMA, write T 16x64 to out.

template <bool W3TAIL>
__global__ __launch_bounds__(256, 6) void fused_agg_gemm_k(
    const float* __restrict__ h, const int* __restrict__ offs,
    const int* __restrict__ esrc, const float* __restrict__ inv,
    const short* __restrict__ WhF, const short* __restrict__ WlF,
    const float* __restrict__ bias,
    const short* __restrict__ W3hF, const short* __restrict__ W3lF,
    float* __restrict__ out, int n) {
    __shared__ float rows[16][132];  // +4 pad
    int wave = threadIdx.x >> 6;
    int lane = threadIdx.x & 63;
    int rowbase = blockIdx.x * 16;

    // ---- phase 1: aggregate 4 rows per wave ----
    {
        int half = lane >> 5;
        int l5 = lane & 31;
        const float4* __restrict__ h4 = (const float4*)h;
#pragma unroll
        for (int it = 0; it < 2; ++it) {
            int r = wave * 4 + it * 2 + half;
            int node = rowbase + r;
            float ax = 0.f, ay = 0.f, az = 0.f, aw = 0.f;
            if (node < n) {
                int beg = offs[node], end = offs[node + 1];
                int j = beg;
                for (; j + 4 <= end; j += 4) {
                    int s0 = esrc[j], s1 = esrc[j + 1];
                    int s2 = esrc[j + 2], s3 = esrc[j + 3];
                    float4 v0 = h4[(size_t)s0 * 32 + l5];
                    float4 v1 = h4[(size_t)s1 * 32 + l5];
                    float4 v2 = h4[(size_t)s2 * 32 + l5];
                    float4 v3 = h4[(size_t)s3 * 32 + l5];
                    ax += (v0.x + v1.x) + (v2.x + v3.x);
                    ay += (v0.y + v1.y) + (v2.y + v3.y);
                    az += (v0.z + v1.z) + (v2.z + v3.z);
                    aw += (v0.w + v1.w) + (v2.w + v3.w);
                }
                for (; j < end; ++j) {
                    float4 v = h4[(size_t)esrc[j] * 32 + l5];
                    ax += v.x; ay += v.y; az += v.z; aw += v.w;
                }
                float sc = inv[node];
                ax *= sc; ay *= sc; az *= sc; aw *= sc;
            }
            float4 r4; r4.x = ax; r4.y = ay; r4.z = az; r4.w = aw;
            *(float4*)&rows[r][l5 * 4] = r4;
        }
    }
    __syncthreads();

    // ---- phase 2: MFMA, wave w = cols w*32..+32, rows 0..15 ----
    int g = lane >> 4, cl = lane & 15;
    short8v ah[4], al[4];
#pragma unroll
    for (int ks = 0; ks < 4; ++ks) {
        const float* rp = &rows[cl][ks * 32 + g * 4];
        float4 aL = *(const float4*)rp;
        float4 aH = *(const float4*)(rp + 16);
#define SPLIT1(D, J, V)                                                     \
        {                                                                   \
            unsigned u = __float_as_uint(V);                                \
            D##h[ks][J] = (short)(u >> 16);                                 \
            float res = (V) - __uint_as_float(u & 0xFFFF0000u);             \
            D##l[ks][J] = (short)(__float_as_uint(res) >> 16);              \
        }
        SPLIT1(a, 0, aL.x) SPLIT1(a, 1, aL.y) SPLIT1(a, 2, aL.z) SPLIT1(a, 3, aL.w)
        SPLIT1(a, 4, aH.x) SPLIT1(a, 5, aH.y) SPLIT1(a, 6, aH.z) SPLIT1(a, 7, aH.w)
#undef SPLIT1
    }
    if (W3TAIL) __syncthreads();  // all A-frag reads done before h2 overwrites

    f32x4 acc[2];
    acc[0] = (f32x4){0.f, 0.f, 0.f, 0.f};
    acc[1] = (f32x4){0.f, 0.f, 0.f, 0.f};
#pragma unroll
    for (int ks = 0; ks < 4; ++ks) {
#pragma unroll
        for (int t = 0; t < 2; ++t) {
            int tileIdx = wave * 2 + t;
            size_t fo = ((size_t)(tileIdx * 4 + ks) * 64 + lane) * 8;
            short8v bh = *(const short8v*)(WhF + fo);
            short8v bl = *(const short8v*)(WlF + fo);
            acc[t] = __builtin_amdgcn_mfma_f32_16x16x32_bf16(ah[ks], bh, acc[t], 0, 0, 0);
            acc[t] = __builtin_amdgcn_mfma_f32_16x16x32_bf16(al[ks], bh, acc[t], 0, 0, 0);
            acc[t] = __builtin_amdgcn_mfma_f32_16x16x32_bf16(ah[ks], bl, acc[t], 0, 0, 0);
        }
    }

#pragma unroll
    for (int t = 0; t < 2; ++t) {
        int col = (wave * 2 + t) * 16 + cl;
        float bv = bias[col];
#pragma unroll
        for (int r = 0; r < 4; ++r) {
            float v = fmaxf(acc[t][r] + bv, 0.f);
            if (!W3TAIL) {
                int gr = rowbase + g * 4 + r;
                if (gr < n) out[(size_t)gr * 128 + col] = v;
            } else {
                rows[g * 4 + r][col] = v;  // h2 back into LDS
            }
        }
    }

    if (W3TAIL) {
        __syncthreads();
        // ---- phase 3: T = h2 @ W3 (wave w = col-tile w, 16 cols) ----
        f32x4 acc3 = {0.f, 0.f, 0.f, 0.f};
#pragma unroll
        for (int ks = 0; ks < 4; ++ks) {
            const float* rp = &rows[cl][ks * 32 + g * 4];
            float4 aL = *(const float4*)rp;
            float4 aH = *(const float4*)(rp + 16);
            short8v bh2, bl2;
#define SPLIT1(J, V)                                                        \
            {                                                               \
                unsigned u = __float_as_uint(V);                            \
                bh2[J] = (short)(u >> 16);                                  \
                float res = (V) - __uint_as_float(u & 0xFFFF0000u);         \
                bl2[J] = (short)(__float_as_uint(res) >> 16);               \
            }
            SPLIT1(0, aL.x) SPLIT1(1, aL.y) SPLIT1(2, aL.z) SPLIT1(3, aL.w)
            SPLIT1(4, aH.x) SPLIT1(5, aH.y) SPLIT1(6, aH.z) SPLIT1(7, aH.w)
#undef SPLIT1
            size_t fo = ((size_t)(wave * 4 + ks) * 64 + lane) * 8;
            short8v wh = *(const short8v*)(W3hF + fo);
            short8v wl = *(const short8v*)(W3lF + fo);
            acc3 = __builtin_amdgcn_mfma_f32_16x16x32_bf16(bh2, wh, acc3, 0, 0, 0);
            acc3 = __builtin_amdgcn_mfma_f32_16x16x32_bf16(bl2, wh, acc3, 0, 0, 0);
            acc3 = __builtin_amdgcn_mfma_f32_16x16x32_bf16(bh2, wl, acc3, 0, 0, 0);
        }
        int col3 = wave * 16 + cl;
#pragma unroll
        for (int r = 0; r < 4; ++r) {
            int gr = rowbase + g * 4 + r;
            if (gr < n) out[(size_t)gr * 64 + col3] = acc3[r];
        }
    }
}

// ---------------- agg64: 4 nodes/wave, float4/lane, fused bias, final out ------

__global__ __launch_bounds__(256) void agg64_k(const float* __restrict__ t64,
                                               const int* __restrict__ offs,
                                               const int* __restrict__ esrc,
                                               const float* __restrict__ inv,
                                               const float* __restrict__ bias,
                                               float* __restrict__ out, int n) {
    int gt = blockIdx.x * 256 + threadIdx.x;
    int wv = gt >> 6;
    int q = (threadIdx.x >> 4) & 3;
    int l4 = threadIdx.x & 15;
    int node = wv * 4 + q;
    if (node >= n) return;
    int beg = offs[node], end = offs[node + 1];
    const float4* __restrict__ h4 = (const float4*)t64;
    float4 a = {0.f, 0.f, 0.f, 0.f};
    int j = beg;
    for (; j + 4 <= end; j += 4) {
        int s0 = esrc[j], s1 = esrc[j + 1], s2 = esrc[j + 2], s3 = esrc[j + 3];
        float4 v0 = h4[(size_t)s0 * 16 + l4];
        float4 v1 = h4[(size_t)s1 * 16 + l4];
        float4 v2 = h4[(size_t)s2 * 16 + l4];
        float4 v3 = h4[(size_t)s3 * 16 + l4];
        a.x += (v0.x + v1.x) + (v2.x + v3.x);
        a.y += (v0.y + v1.y) + (v2.y + v3.y);
        a.z += (v0.z + v1.z) + (v2.z + v3.z);
        a.w += (v0.w + v1.w) + (v2.w + v3.w);
    }
    for (; j < end; ++j) {
        float4 v = h4[(size_t)esrc[j] * 16 + l4];
        a.x += v.x; a.y += v.y; a.z += v.z; a.w += v.w;
    }
    float sc = inv[node];
    float4 b = ((const float4*)bias)[l4];
    float4 r;
    r.x = a.x * sc + b.x; r.y = a.y * sc + b.y;
    r.z = a.z * sc + b.z; r.w = a.w * sc + b.w;
    ((float4*)out)[(size_t)node * 16 + l4] = r;
}

// ---------------- launch ----------------

extern "C" void kernel_launch(void* const* d_in, const int* in_sizes, int n_in,
                              void* d_out, int out_size, void* d_ws, size_t ws_size,
                              hipStream_t stream) {
    const int N = N_NODES, E = N_EDGES;
    const float* feat = (const float*)d_in[0];
    const int* src = (const int*)d_in[1];
    const int* dst = (const int*)d_in[2];
    const float* W1 = (const float*)d_in[3];
    const float* b1 = (const float*)d_in[4];
    const float* W2 = (const float*)d_in[5];
    const float* b2 = (const float*)d_in[6];
    const float* W3 = (const float*)d_in[7];
    const float* b3 = (const float*)d_in[8];
    float* out = (float*)d_out;

    const int nScanBlocks = (N + SCAN_CHUNK - 1) / SCAN_CHUNK;  // 49

    // workspace layout
    float* B0 = (float*)d_ws;                       // N*128 f32 (T uses N*64)
    float* B1 = B0 + (size_t)N * 128;               // N*128 f32
    int* deg = (int*)(B1 + (size_t)N * 128);        // N
    float* invd = (float*)(deg + N);                // N
    int* offs = (int*)(invd + N);                   // N+2 (pad -> cursor 8B-aligned)
    int* cursor = offs + N + 2;                     // N
    int* esrc = cursor + N;                         // E
    int* blockSums = esrc + E;                      // nScanBlocks
    // WF buffers alias `cursor` (dead after fill_csr_k): 160KB <= N*4B
    short* W1h = (short*)cursor;
    short* W1l = W1h + 16384;
    short* W2h = W1l + 16384;
    short* W2l = W2h + 16384;
    short* W3h = W2l + 16384;
    short* W3l = W3h + 8192;

    // --- CSR build ---
    hipMemsetAsync(deg, 0, (size_t)N * sizeof(int), stream);
    count_deg_k<<<(E + 255) / 256, 256, 0, stream>>>(dst, deg, E);
    scan_part_k<<<nScanBlocks, 256, 0, stream>>>(deg, blockSums, N);
    scan_blocks_k<<<1, 64, 0, stream>>>(blockSums, nScanBlocks, offs, N);
    scan_final_k<<<nScanBlocks, 256, 0, stream>>>(deg, blockSums, offs, cursor, invd, N);
    fill_csr_k<<<(E + 255) / 256, 256, 0, stream>>>(src, dst, cursor, esrc, E);

    // --- weight prep (after fill_csr: WF aliases cursor) ---
    prep_all_k<<<20, 256, 0, stream>>>(W1, W2, W3, W1h, W1l, W2h, W2l, W3h, W3l);

    const int fusedGrid = (N + 15) / 16;     // 3125
    const int agg64Grid = (N + 15) / 16;

    // --- layer 1: fused agg+gemm (feat -> H in B1) ---
    fused_agg_gemm_k<false><<<fusedGrid, 256, 0, stream>>>(
        feat, offs, esrc, invd, W1h, W1l, b1, nullptr, nullptr, B1, N);
    // --- layer 2 + 3a: fused agg+gemm+W3 (H -> T in B0, T = h2 @ W3) ---
    fused_agg_gemm_k<true><<<fusedGrid, 256, 0, stream>>>(
        B1, offs, esrc, invd, W2h, W2l, b2, W3h, W3l, B0, N);
    // --- layer 3b: agg64(T) + b3 -> out ---
    agg64_k<<<agg64Grid, 256, 0, stream>>>(B0, offs, esrc, invd, b3, out, N);
}

// Round 11
// 247.867 us; speedup vs baseline: 1.9010x; 1.1337x over previous
//
#include <hip/hip_runtime.h>
#include <stdint.h>

// GCN: 3-layer GraphConv (norm='right'), N=50000, E=600000, 128->128->128->64.
//
// R1: hierarchical scan (110us -> ~5us).                        [442us]
// R3: MFMA split-bf16 GEMM (latency-bound, neutral alone).
// R4: grid x4 + agg float4 -> TA-transaction diagnosis.         [431us]
// R5: fragment-major W + XCD swizzle: gemm off top-5.           [337us]
// R7: fused agg128+gemm128 (LDS + MFMA).                        [305us]
// R8: 32 rows/block: occ 28->53%, gather 2.6->3.05 TB/s.        [292us]
// R9: 16 rows/block + W3 tail fusion. occ 65% but gather STUCK at 3.05 TB/s
//     (FETCH 133MB invariant): L2-miss path saturated.          [281us]
// R10: cut bytes, not rate: bf16 activations on all gathered tensors
//     (feat/h1/T). Rounding noise is mean-aggregated away (safe). Gather
//     rows 512B->256B. feat-cvt folded into count_deg; prep merged into
//     fill_csr (W bufs un-aliased). 9 launches.

#define N_NODES 50000
#define N_EDGES 600000
#define SCAN_CHUNK 1024
#define FILL_BLOCKS ((N_EDGES + 255) / 256)   // 2344

typedef __attribute__((ext_vector_type(8))) short short8v;
typedef __attribute__((ext_vector_type(4))) float f32x4;

__device__ __forceinline__ unsigned short f2bf(float f) {  // RNE
    unsigned u = __float_as_uint(f);
    unsigned r = (u + 0x7fffu + ((u >> 16) & 1u)) >> 16;
    return (unsigned short)r;
}

// ---------------- CSR build ----------------

// count degrees + convert feat (fp32 -> bf16 packed), independent work
__global__ void count_cvt_k(const int* __restrict__ dst, int* __restrict__ deg,
                            const float* __restrict__ feat, uint4* __restrict__ featB,
                            int e, int n8) {
    int i = blockIdx.x * 256 + threadIdx.x;
    if (i < e) atomicAdd(&deg[dst[i]], 1);
    if (i < n8) {
        const float4* f4 = (const float4*)feat;
        float4 a = f4[(size_t)i * 2];
        float4 b = f4[(size_t)i * 2 + 1];
        uint4 o;
        o.x = (unsigned)f2bf(a.x) | ((unsigned)f2bf(a.y) << 16);
        o.y = (unsigned)f2bf(a.z) | ((unsigned)f2bf(a.w) << 16);
        o.z = (unsigned)f2bf(b.x) | ((unsigned)f2bf(b.y) << 16);
        o.w = (unsigned)f2bf(b.z) | ((unsigned)f2bf(b.w) << 16);
        featB[i] = o;
    }
}

__global__ __launch_bounds__(256) void scan_part_k(const int* __restrict__ deg,
                                                   int* __restrict__ blockSums, int n) {
    __shared__ int red[256];
    int t = threadIdx.x;
    int base = blockIdx.x * SCAN_CHUNK + t * 4;
    int s = 0;
#pragma unroll
    for (int k = 0; k < 4; ++k) {
        int i = base + k;
        if (i < n) s += deg[i];
    }
    red[t] = s;
    __syncthreads();
    for (int off = 128; off > 0; off >>= 1) {
        if (t < off) red[t] += red[t + off];
        __syncthreads();
    }
    if (t == 0) blockSums[blockIdx.x] = red[0];
}

__global__ void scan_blocks_k(int* __restrict__ blockSums, int nb,
                              int* __restrict__ offs, int n) {
    if (threadIdx.x == 0 && blockIdx.x == 0) {
        int run = 0;
        for (int i = 0; i < nb; ++i) {
            int v = blockSums[i];
            blockSums[i] = run;
            run += v;
        }
        offs[n] = run;
    }
}

__global__ __launch_bounds__(256) void scan_final_k(const int* __restrict__ deg,
                                                    const int* __restrict__ blockSums,
                                                    int* __restrict__ offs,
                                                    int* __restrict__ cursor,
                                                    float* __restrict__ inv, int n) {
    __shared__ int red[256];
    int t = threadIdx.x;
    int base = blockIdx.x * SCAN_CHUNK + t * 4;
    int v[4];
    int s = 0;
#pragma unroll
    for (int k = 0; k < 4; ++k) {
        int i = base + k;
        v[k] = (i < n) ? deg[i] : 0;
        s += v[k];
    }
    red[t] = s;
    __syncthreads();
    for (int off = 1; off < 256; off <<= 1) {
        int x = (t >= off) ? red[t - off] : 0;
        __syncthreads();
        red[t] += x;
        __syncthreads();
    }
    int run = blockSums[blockIdx.x] + red[t] - s;
#pragma unroll
    for (int k = 0; k < 4; ++k) {
        int i = base + k;
        if (i < n) {
            offs[i] = run;
            cursor[i] = run;
            inv[i] = 1.0f / (float)(v[k] > 0 ? v[k] : 1);
            run += v[k];
        }
    }
}

// ---- weight prep helper: W[K][NC] fp32 -> fragment-major split-bf16 hi/lo ----
// Frag idx: tile T (NC/16), kstep ks (4), lane l (64): 8 bf16 at (((T*4+ks)*64)+l)*8.
// Lane l=g*16+cl holds W[k][T*16+cl], k=ks*32+g*4+(j&3)+16*(j>>2).

__device__ __forceinline__ void prep_one(const float* __restrict__ W, short* hiF,
                                         short* loF, int NC, int idx) {
    int lane = idx & 63;
    int ks = (idx >> 6) & 3;
    int T = idx >> 8;
    int g = lane >> 4, cl = lane & 15;
    int col = T * 16 + cl;
    short8v h, l;
#pragma unroll
    for (int j = 0; j < 8; ++j) {
        int k = ks * 32 + g * 4 + (j & 3) + ((j >> 2) << 4);
        float w = W[(size_t)k * NC + col];
        unsigned u = __float_as_uint(w);
        h[j] = (short)(u >> 16);
        float res = w - __uint_as_float(u & 0xFFFF0000u);
        l[j] = (short)(__float_as_uint(res) >> 16);
    }
    ((short8v*)hiF)[idx] = h;
    ((short8v*)loF)[idx] = l;
}

// fill CSR (blocks < FILL_BLOCKS) + weight prep (blocks >= FILL_BLOCKS)
__global__ void fill_prep_k(const int* __restrict__ src, const int* __restrict__ dst,
                            int* __restrict__ cursor, int* __restrict__ esrc, int e,
                            const float* __restrict__ W1, const float* __restrict__ W2,
                            const float* __restrict__ W3,
                            short* W1h, short* W1l, short* W2h, short* W2l,
                            short* W3h, short* W3l) {
    int b = blockIdx.x;
    if (b < FILL_BLOCKS) {
        int i = b * 256 + threadIdx.x;
        if (i < e) {
            int p = atomicAdd(&cursor[dst[i]], 1);
            esrc[p] = src[i];
        }
    } else {
        int idx = (b - FILL_BLOCKS) * 256 + threadIdx.x;
        if (idx < 2048) prep_one(W1, W1h, W1l, 128, idx);
        else if (idx < 4096) prep_one(W2, W2h, W2l, 128, idx - 2048);
        else if (idx < 5120) prep_one(W3, W3h, W3l, 64, idx - 4096);
    }
}

// ---------------- fused agg(bf16 gather) + gemm (+ optional W3 tail) ----------
// Block = 256 thr = 4 waves = 16 dst rows. Gather rows are bf16 (256B):
// 32 lanes x uint2 (4 bf16 each), unpack via shift/and, accumulate f32.
// Phase 2: split-bf16 MFMA vs frag-major W; outputs stored bf16.

template <bool W3TAIL>
__global__ __launch_bounds__(256, 6) void fused_agg_gemm_k(
    const unsigned short* __restrict__ hB, const int* __restrict__ offs,
    const int* __restrict__ esrc, const float* __restrict__ inv,
    const short* __restrict__ WhF, const short* __restrict__ WlF,
    const float* __restrict__ bias,
    const short* __restrict__ W3hF, const short* __restrict__ W3lF,
    unsigned short* __restrict__ outB, int n) {
    __shared__ float rows[16][132];  // +4 pad
    int wave = threadIdx.x >> 6;
    int lane = threadIdx.x & 63;
    int rowbase = blockIdx.x * 16;

    // ---- phase 1: aggregate 4 rows per wave (bf16 gather) ----
    {
        int half = lane >> 5;
        int l5 = lane & 31;
        const uint2* __restrict__ h2 = (const uint2*)hB;  // 8B = 4 bf16
#pragma unroll
        for (int it = 0; it < 2; ++it) {
            int r = wave * 4 + it * 2 + half;
            int node = rowbase + r;
            float ax = 0.f, ay = 0.f, az = 0.f, aw = 0.f;
            if (node < n) {
                int beg = offs[node], end = offs[node + 1];
                int j = beg;
#define ACC4(V)                                                             \
                {                                                           \
                    ax += __uint_as_float((V).x << 16);                     \
                    ay += __uint_as_float((V).x & 0xffff0000u);             \
                    az += __uint_as_float((V).y << 16);                     \
                    aw += __uint_as_float((V).y & 0xffff0000u);             \
                }
                for (; j + 4 <= end; j += 4) {
                    int s0 = esrc[j], s1 = esrc[j + 1];
                    int s2 = esrc[j + 2], s3 = esrc[j + 3];
                    uint2 v0 = h2[(size_t)s0 * 32 + l5];
                    uint2 v1 = h2[(size_t)s1 * 32 + l5];
                    uint2 v2 = h2[(size_t)s2 * 32 + l5];
                    uint2 v3 = h2[(size_t)s3 * 32 + l5];
                    ACC4(v0) ACC4(v1) ACC4(v2) ACC4(v3)
                }
                for (; j < end; ++j) {
                    uint2 v = h2[(size_t)esrc[j] * 32 + l5];
                    ACC4(v)
                }
#undef ACC4
                float sc = inv[node];
                ax *= sc; ay *= sc; az *= sc; aw *= sc;
            }
            float4 r4; r4.x = ax; r4.y = ay; r4.z = az; r4.w = aw;
            *(float4*)&rows[r][l5 * 4] = r4;
        }
    }
    __syncthreads();

    // ---- phase 2: MFMA, wave w = cols w*32..+32, rows 0..15 ----
    int g = lane >> 4, cl = lane & 15;
    short8v ah[4], al[4];
#pragma unroll
    for (int ks = 0; ks < 4; ++ks) {
        const float* rp = &rows[cl][ks * 32 + g * 4];
        float4 aL = *(const float4*)rp;
        float4 aH = *(const float4*)(rp + 16);
#define SPLIT1(J, V)                                                        \
        {                                                                   \
            unsigned u = __float_as_uint(V);                                \
            ah[ks][J] = (short)(u >> 16);                                   \
            float res = (V) - __uint_as_float(u & 0xFFFF0000u);             \
            al[ks][J] = (short)(__float_as_uint(res) >> 16);                \
        }
        SPLIT1(0, aL.x) SPLIT1(1, aL.y) SPLIT1(2, aL.z) SPLIT1(3, aL.w)
        SPLIT1(4, aH.x) SPLIT1(5, aH.y) SPLIT1(6, aH.z) SPLIT1(7, aH.w)
#undef SPLIT1
    }
    if (W3TAIL) __syncthreads();  // A-frag reads done before h2 overwrites LDS

    f32x4 acc[2];
    acc[0] = (f32x4){0.f, 0.f, 0.f, 0.f};
    acc[1] = (f32x4){0.f, 0.f, 0.f, 0.f};
#pragma unroll
    for (int ks = 0; ks < 4; ++ks) {
#pragma unroll
        for (int t = 0; t < 2; ++t) {
            int tileIdx = wave * 2 + t;
            size_t fo = ((size_t)(tileIdx * 4 + ks) * 64 + lane) * 8;
            short8v bh = *(const short8v*)(WhF + fo);
            short8v bl = *(const short8v*)(WlF + fo);
            acc[t] = __builtin_amdgcn_mfma_f32_16x16x32_bf16(ah[ks], bh, acc[t], 0, 0, 0);
            acc[t] = __builtin_amdgcn_mfma_f32_16x16x32_bf16(al[ks], bh, acc[t], 0, 0, 0);
            acc[t] = __builtin_amdgcn_mfma_f32_16x16x32_bf16(ah[ks], bl, acc[t], 0, 0, 0);
        }
    }

#pragma unroll
    for (int t = 0; t < 2; ++t) {
        int col = (wave * 2 + t) * 16 + cl;
        float bv = bias[col];
#pragma unroll
        for (int r = 0; r < 4; ++r) {
            float v = fmaxf(acc[t][r] + bv, 0.f);
            if (!W3TAIL) {
                int gr = rowbase + g * 4 + r;
                if (gr < n) outB[(size_t)gr * 128 + col] = f2bf(v);
            } else {
                rows[g * 4 + r][col] = v;  // h2 back into LDS (f32)
            }
        }
    }

    if (W3TAIL) {
        __syncthreads();
        // ---- phase 3: T = h2 @ W3 (wave w = col-tile w, 16 cols), bf16 out ----
        f32x4 acc3 = {0.f, 0.f, 0.f, 0.f};
#pragma unroll
        for (int ks = 0; ks < 4; ++ks) {
            const float* rp = &rows[cl][ks * 32 + g * 4];
            float4 aL = *(const float4*)rp;
            float4 aH = *(const float4*)(rp + 16);
            short8v bh2, bl2;
#define SPLIT1(J, V)                                                        \
            {                                                               \
                unsigned u = __float_as_uint(V);                            \
                bh2[J] = (short)(u >> 16);                                  \
                float res = (V) - __uint_as_float(u & 0xFFFF0000u);         \
                bl2[J] = (short)(__float_as_uint(res) >> 16);               \
            }
            SPLIT1(0, aL.x) SPLIT1(1, aL.y) SPLIT1(2, aL.z) SPLIT1(3, aL.w)
            SPLIT1(4, aH.x) SPLIT1(5, aH.y) SPLIT1(6, aH.z) SPLIT1(7, aH.w)
#undef SPLIT1
            size_t fo = ((size_t)(wave * 4 + ks) * 64 + lane) * 8;
            short8v wh = *(const short8v*)(W3hF + fo);
            short8v wl = *(const short8v*)(W3lF + fo);
            acc3 = __builtin_amdgcn_mfma_f32_16x16x32_bf16(bh2, wh, acc3, 0, 0, 0);
            acc3 = __builtin_amdgcn_mfma_f32_16x16x32_bf16(bl2, wh, acc3, 0, 0, 0);
            acc3 = __builtin_amdgcn_mfma_f32_16x16x32_bf16(bh2, wl, acc3, 0, 0, 0);
        }
        int col3 = wave * 16 + cl;
#pragma unroll
        for (int r = 0; r < 4; ++r) {
            int gr = rowbase + g * 4 + r;
            if (gr < n) outB[(size_t)gr * 64 + col3] = f2bf(acc3[r]);
        }
    }
}

// ------- agg64: bf16 T gather (4 nodes/wave, uint2/lane), f32 out + bias -------

__global__ __launch_bounds__(256) void agg64_k(const unsigned short* __restrict__ tB,
                                               const int* __restrict__ offs,
                                               const int* __restrict__ esrc,
                                               const float* __restrict__ inv,
                                               const float* __restrict__ bias,
                                               float* __restrict__ out, int n) {
    int gt = blockIdx.x * 256 + threadIdx.x;
    int wv = gt >> 6;
    int q = (threadIdx.x >> 4) & 3;
    int l4 = threadIdx.x & 15;
    int node = wv * 4 + q;
    if (node >= n) return;
    int beg = offs[node], end = offs[node + 1];
    const uint2* __restrict__ t2 = (const uint2*)tB;  // 8B = 4 bf16; row = 16 uint2
    float ax = 0.f, ay = 0.f, az = 0.f, aw = 0.f;
    int j = beg;
#define ACC4(V)                                                             \
    {                                                                       \
        ax += __uint_as_float((V).x << 16);                                 \
        ay += __uint_as_float((V).x & 0xffff0000u);                         \
        az += __uint_as_float((V).y << 16);                                 \
        aw += __uint_as_float((V).y & 0xffff0000u);                         \
    }
    for (; j + 4 <= end; j += 4) {
        int s0 = esrc[j], s1 = esrc[j + 1], s2 = esrc[j + 2], s3 = esrc[j + 3];
        uint2 v0 = t2[(size_t)s0 * 16 + l4];
        uint2 v1 = t2[(size_t)s1 * 16 + l4];
        uint2 v2 = t2[(size_t)s2 * 16 + l4];
        uint2 v3 = t2[(size_t)s3 * 16 + l4];
        ACC4(v0) ACC4(v1) ACC4(v2) ACC4(v3)
    }
    for (; j < end; ++j) {
        uint2 v = t2[(size_t)esrc[j] * 16 + l4];
        ACC4(v)
    }
#undef ACC4
    float sc = inv[node];
    float4 b = ((const float4*)bias)[l4];
    float4 r;
    r.x = ax * sc + b.x; r.y = ay * sc + b.y;
    r.z = az * sc + b.z; r.w = aw * sc + b.w;
    ((float4*)out)[(size_t)node * 16 + l4] = r;
}

// ---------------- launch ----------------

extern "C" void kernel_launch(void* const* d_in, const int* in_sizes, int n_in,
                              void* d_out, int out_size, void* d_ws, size_t ws_size,
                              hipStream_t stream) {
    const int N = N_NODES, E = N_EDGES;
    const float* feat = (const float*)d_in[0];
    const int* src = (const int*)d_in[1];
    const int* dst = (const int*)d_in[2];
    const float* W1 = (const float*)d_in[3];
    const float* b1 = (const float*)d_in[4];
    const float* W2 = (const float*)d_in[5];
    const float* b2 = (const float*)d_in[6];
    const float* W3 = (const float*)d_in[7];
    const float* b3 = (const float*)d_in[8];
    float* out = (float*)d_out;

    const int nScanBlocks = (N + SCAN_CHUNK - 1) / SCAN_CHUNK;  // 49

    // workspace layout (int units from base)
    float* B0 = (float*)d_ws;                       // N*128 f32 region (T bf16 here)
    float* B1 = B0 + (size_t)N * 128;               // N*128 f32 region (h1 bf16 here)
    int* deg = (int*)(B1 + (size_t)N * 128);        // N
    float* invd = (float*)(deg + N);                // N
    int* offs = (int*)(invd + N);                   // N+2
    int* cursor = offs + N + 2;                     // N
    int* esrc = cursor + N;                         // E
    int* blockSums = esrc + E;                      // 64 (padded)
    uintptr_t p = (uintptr_t)(blockSums + 64);
    p = (p + 15) & ~(uintptr_t)15;
    unsigned short* featB = (unsigned short*)p;     // N*128 bf16 (12.8MB)
    short* W1h = (short*)(featB + (size_t)N * 128); // frag-major W bufs (160KB)
    short* W1l = W1h + 16384;
    short* W2h = W1l + 16384;
    short* W2l = W2h + 16384;
    short* W3h = W2l + 16384;
    short* W3l = W3h + 8192;

    unsigned short* h1B = (unsigned short*)B1;      // h1 bf16, N*128
    unsigned short* tB = (unsigned short*)B0;       // T bf16, N*64

    // --- CSR build + feat cvt ---
    hipMemsetAsync(deg, 0, (size_t)N * sizeof(int), stream);
    const int n8 = N * 128 / 8;  // 800000 convert threads
    count_cvt_k<<<(n8 + 255) / 256, 256, 0, stream>>>(dst, deg, feat, (uint4*)featB,
                                                      E, n8);
    scan_part_k<<<nScanBlocks, 256, 0, stream>>>(deg, blockSums, N);
    scan_blocks_k<<<1, 64, 0, stream>>>(blockSums, nScanBlocks, offs, N);
    scan_final_k<<<nScanBlocks, 256, 0, stream>>>(deg, blockSums, offs, cursor, invd, N);
    fill_prep_k<<<FILL_BLOCKS + 20, 256, 0, stream>>>(src, dst, cursor, esrc, E,
                                                      W1, W2, W3, W1h, W1l, W2h, W2l,
                                                      W3h, W3l);

    const int fusedGrid = (N + 15) / 16;     // 3125
    const int agg64Grid = (N + 15) / 16;

    // --- layer 1: fused agg+gemm (featB -> h1B bf16) ---
    fused_agg_gemm_k<false><<<fusedGrid, 256, 0, stream>>>(
        featB, offs, esrc, invd, W1h, W1l, b1, nullptr, nullptr, h1B, N);
    // --- layer 2 + 3a: fused agg+gemm+W3 (h1B -> T bf16) ---
    fused_agg_gemm_k<true><<<fusedGrid, 256, 0, stream>>>(
        h1B, offs, esrc, invd, W2h, W2l, b2, W3h, W3l, tB, N);
    // --- layer 3b: agg64(T) + b3 -> out (f32) ---
    agg64_k<<<agg64Grid, 256, 0, stream>>>(tB, offs, esrc, invd, b3, out, N);
}

// Round 13
// 243.784 us; speedup vs baseline: 1.9329x; 1.0167x over previous
//
#include <hip/hip_runtime.h>
#include <stdint.h>

// GCN: 3-layer GraphConv (norm='right'), N=50000, E=600000, 128->128->128->64.
//
// R1: hierarchical scan (110us -> ~5us).                        [442us]
// R4/R5: MFMA split-bf16 + fragment-major W + XCD swizzle.      [337us]
// R7/R8/R9: fused agg+gemm+W3tail, occupancy tuning.            [281us]
// R10: bf16 activations on all gathered tensors (rows 512->256B),
//     absmax 1.95e-3 (threshold 5.43e-3).                       [248us]
// R11: (a) scan_blocks_k deleted (each scan_final block sums <=49 blockSums
//     itself; offs[N]=E static) -> 8 dispatches; (b) fused kernels
//     launch_bounds(256,6)->(256,8): occupancy ceiling 24->32 waves/CU.
// R12: resubmit (GPU acquisition timeout, no data).

#define N_NODES 50000
#define N_EDGES 600000
#define SCAN_CHUNK 1024
#define FILL_BLOCKS ((N_EDGES + 255) / 256)   // 2344

typedef __attribute__((ext_vector_type(8))) short short8v;
typedef __attribute__((ext_vector_type(4))) float f32x4;

__device__ __forceinline__ unsigned short f2bf(float f) {  // RNE
    unsigned u = __float_as_uint(f);
    unsigned r = (u + 0x7fffu + ((u >> 16) & 1u)) >> 16;
    return (unsigned short)r;
}

// ---------------- CSR build ----------------

// count degrees + convert feat (fp32 -> bf16 packed), independent work
__global__ void count_cvt_k(const int* __restrict__ dst, int* __restrict__ deg,
                            const float* __restrict__ feat, uint4* __restrict__ featB,
                            int e, int n8) {
    int i = blockIdx.x * 256 + threadIdx.x;
    if (i < e) atomicAdd(&deg[dst[i]], 1);
    if (i < n8) {
        const float4* f4 = (const float4*)feat;
        float4 a = f4[(size_t)i * 2];
        float4 b = f4[(size_t)i * 2 + 1];
        uint4 o;
        o.x = (unsigned)f2bf(a.x) | ((unsigned)f2bf(a.y) << 16);
        o.y = (unsigned)f2bf(a.z) | ((unsigned)f2bf(a.w) << 16);
        o.z = (unsigned)f2bf(b.x) | ((unsigned)f2bf(b.y) << 16);
        o.w = (unsigned)f2bf(b.z) | ((unsigned)f2bf(b.w) << 16);
        featB[i] = o;
    }
}

__global__ __launch_bounds__(256) void scan_part_k(const int* __restrict__ deg,
                                                   int* __restrict__ blockSums, int n) {
    __shared__ int red[256];
    int t = threadIdx.x;
    int base = blockIdx.x * SCAN_CHUNK + t * 4;
    int s = 0;
#pragma unroll
    for (int k = 0; k < 4; ++k) {
        int i = base + k;
        if (i < n) s += deg[i];
    }
    red[t] = s;
    __syncthreads();
    for (int off = 128; off > 0; off >>= 1) {
        if (t < off) red[t] += red[t + off];
        __syncthreads();
    }
    if (t == 0) blockSums[blockIdx.x] = red[0];
}

// local scan; block prefix computed in-block from blockSums (<=64 entries);
// offs[N]=E written statically. Also emits cursor + inv_deg.
__global__ __launch_bounds__(256) void scan_final_k(const int* __restrict__ deg,
                                                    const int* __restrict__ blockSums,
                                                    int* __restrict__ offs,
                                                    int* __restrict__ cursor,
                                                    float* __restrict__ inv,
                                                    int n, int nb, int e) {
    __shared__ int red[256];
    __shared__ int bs[64];
    int t = threadIdx.x;
    if (t < 64) bs[t] = (t < nb && t < (int)blockIdx.x) ? blockSums[t] : 0;
    int base = blockIdx.x * SCAN_CHUNK + t * 4;
    int v[4];
    int s = 0;
#pragma unroll
    for (int k = 0; k < 4; ++k) {
        int i = base + k;
        v[k] = (i < n) ? deg[i] : 0;
        s += v[k];
    }
    red[t] = s;
    __syncthreads();
    int bpfx = 0;
#pragma unroll
    for (int i = 0; i < 64; ++i) bpfx += bs[i];
    for (int off = 1; off < 256; off <<= 1) {
        int x = (t >= off) ? red[t - off] : 0;
        __syncthreads();
        red[t] += x;
        __syncthreads();
    }
    int run = bpfx + red[t] - s;
#pragma unroll
    for (int k = 0; k < 4; ++k) {
        int i = base + k;
        if (i < n) {
            offs[i] = run;
            cursor[i] = run;
            inv[i] = 1.0f / (float)(v[k] > 0 ? v[k] : 1);
            run += v[k];
        }
    }
    if (blockIdx.x == 0 && t == 0) offs[n] = e;
}

// ---- weight prep helper: W[K][NC] fp32 -> fragment-major split-bf16 hi/lo ----
// Frag idx: tile T (NC/16), kstep ks (4), lane l (64): 8 bf16 at (((T*4+ks)*64)+l)*8.
// Lane l=g*16+cl holds W[k][T*16+cl], k=ks*32+g*4+(j&3)+16*(j>>2).

__device__ __forceinline__ void prep_one(const float* __restrict__ W, short* hiF,
                                         short* loF, int NC, int idx) {
    int lane = idx & 63;
    int ks = (idx >> 6) & 3;
    int T = idx >> 8;
    int g = lane >> 4, cl = lane & 15;
    int col = T * 16 + cl;
    short8v h, l;
#pragma unroll
    for (int j = 0; j < 8; ++j) {
        int k = ks * 32 + g * 4 + (j & 3) + ((j >> 2) << 4);
        float w = W[(size_t)k * NC + col];
        unsigned u = __float_as_uint(w);
        h[j] = (short)(u >> 16);
        float res = w - __uint_as_float(u & 0xFFFF0000u);
        l[j] = (short)(__float_as_uint(res) >> 16);
    }
    ((short8v*)hiF)[idx] = h;
    ((short8v*)loF)[idx] = l;
}

// fill CSR (blocks < FILL_BLOCKS) + weight prep (blocks >= FILL_BLOCKS)
__global__ void fill_prep_k(const int* __restrict__ src, const int* __restrict__ dst,
                            int* __restrict__ cursor, int* __restrict__ esrc, int e,
                            const float* __restrict__ W1, const float* __restrict__ W2,
                            const float* __restrict__ W3,
                            short* W1h, short* W1l, short* W2h, short* W2l,
                            short* W3h, short* W3l) {
    int b = blockIdx.x;
    if (b < FILL_BLOCKS) {
        int i = b * 256 + threadIdx.x;
        if (i < e) {
            int p = atomicAdd(&cursor[dst[i]], 1);
            esrc[p] = src[i];
        }
    } else {
        int idx = (b - FILL_BLOCKS) * 256 + threadIdx.x;
        if (idx < 2048) prep_one(W1, W1h, W1l, 128, idx);
        else if (idx < 4096) prep_one(W2, W2h, W2l, 128, idx - 2048);
        else if (idx < 5120) prep_one(W3, W3h, W3l, 64, idx - 4096);
    }
}

// ---------------- fused agg(bf16 gather) + gemm (+ optional W3 tail) ----------
// Block = 256 thr = 4 waves = 16 dst rows. Gather rows are bf16 (256B):
// 32 lanes x uint2 (4 bf16 each), unpack via shift/and, accumulate f32.
// Phase 2: split-bf16 MFMA vs frag-major W; outputs stored bf16.

template <bool W3TAIL>
__global__ __launch_bounds__(256, 8) void fused_agg_gemm_k(
    const unsigned short* __restrict__ hB, const int* __restrict__ offs,
    const int* __restrict__ esrc, const float* __restrict__ inv,
    const short* __restrict__ WhF, const short* __restrict__ WlF,
    const float* __restrict__ bias,
    const short* __restrict__ W3hF, const short* __restrict__ W3lF,
    unsigned short* __restrict__ outB, int n) {
    __shared__ float rows[16][132];  // +4 pad
    int wave = threadIdx.x >> 6;
    int lane = threadIdx.x & 63;
    int rowbase = blockIdx.x * 16;

    // ---- phase 1: aggregate 4 rows per wave (bf16 gather) ----
    {
        int half = lane >> 5;
        int l5 = lane & 31;
        const uint2* __restrict__ h2 = (const uint2*)hB;  // 8B = 4 bf16
#pragma unroll
        for (int it = 0; it < 2; ++it) {
            int r = wave * 4 + it * 2 + half;
            int node = rowbase + r;
            float ax = 0.f, ay = 0.f, az = 0.f, aw = 0.f;
            if (node < n) {
                int beg = offs[node], end = offs[node + 1];
                int j = beg;
#define ACC4(V)                                                             \
                {                                                           \
                    ax += __uint_as_float((V).x << 16);                     \
                    ay += __uint_as_float((V).x & 0xffff0000u);             \
                    az += __uint_as_float((V).y << 16);                     \
                    aw += __uint_as_float((V).y & 0xffff0000u);             \
                }
                for (; j + 4 <= end; j += 4) {
                    int s0 = esrc[j], s1 = esrc[j + 1];
                    int s2 = esrc[j + 2], s3 = esrc[j + 3];
                    uint2 v0 = h2[(size_t)s0 * 32 + l5];
                    uint2 v1 = h2[(size_t)s1 * 32 + l5];
                    uint2 v2 = h2[(size_t)s2 * 32 + l5];
                    uint2 v3 = h2[(size_t)s3 * 32 + l5];
                    ACC4(v0) ACC4(v1) ACC4(v2) ACC4(v3)
                }
                for (; j < end; ++j) {
                    uint2 v = h2[(size_t)esrc[j] * 32 + l5];
                    ACC4(v)
                }
#undef ACC4
                float sc = inv[node];
                ax *= sc; ay *= sc; az *= sc; aw *= sc;
            }
            float4 r4; r4.x = ax; r4.y = ay; r4.z = az; r4.w = aw;
            *(float4*)&rows[r][l5 * 4] = r4;
        }
    }
    __syncthreads();

    // ---- phase 2: MFMA, wave w = cols w*32..+32, rows 0..15 ----
    int g = lane >> 4, cl = lane & 15;
    short8v ah[4], al[4];
#pragma unroll
    for (int ks = 0; ks < 4; ++ks) {
        const float* rp = &rows[cl][ks * 32 + g * 4];
        float4 aL = *(const float4*)rp;
        float4 aH = *(const float4*)(rp + 16);
#define SPLIT1(J, V)                                                        \
        {                                                                   \
            unsigned u = __float_as_uint(V);                                \
            ah[ks][J] = (short)(u >> 16);                                   \
            float res = (V) - __uint_as_float(u & 0xFFFF0000u);             \
            al[ks][J] = (short)(__float_as_uint(res) >> 16);                \
        }
        SPLIT1(0, aL.x) SPLIT1(1, aL.y) SPLIT1(2, aL.z) SPLIT1(3, aL.w)
        SPLIT1(4, aH.x) SPLIT1(5, aH.y) SPLIT1(6, aH.z) SPLIT1(7, aH.w)
#undef SPLIT1
    }
    if (W3TAIL) __syncthreads();  // A-frag reads done before h2 overwrites LDS

    f32x4 acc[2];
    acc[0] = (f32x4){0.f, 0.f, 0.f, 0.f};
    acc[1] = (f32x4){0.f, 0.f, 0.f, 0.f};
#pragma unroll
    for (int ks = 0; ks < 4; ++ks) {
#pragma unroll
        for (int t = 0; t < 2; ++t) {
            int tileIdx = wave * 2 + t;
            size_t fo = ((size_t)(tileIdx * 4 + ks) * 64 + lane) * 8;
            short8v bh = *(const short8v*)(WhF + fo);
            short8v bl = *(const short8v*)(WlF + fo);
            acc[t] = __builtin_amdgcn_mfma_f32_16x16x32_bf16(ah[ks], bh, acc[t], 0, 0, 0);
            acc[t] = __builtin_amdgcn_mfma_f32_16x16x32_bf16(al[ks], bh, acc[t], 0, 0, 0);
            acc[t] = __builtin_amdgcn_mfma_f32_16x16x32_bf16(ah[ks], bl, acc[t], 0, 0, 0);
        }
    }

#pragma unroll
    for (int t = 0; t < 2; ++t) {
        int col = (wave * 2 + t) * 16 + cl;
        float bv = bias[col];
#pragma unroll
        for (int r = 0; r < 4; ++r) {
            float v = fmaxf(acc[t][r] + bv, 0.f);
            if (!W3TAIL) {
                int gr = rowbase + g * 4 + r;
                if (gr < n) outB[(size_t)gr * 128 + col] = f2bf(v);
            } else {
                rows[g * 4 + r][col] = v;  // h2 back into LDS (f32)
            }
        }
    }

    if (W3TAIL) {
        __syncthreads();
        // ---- phase 3: T = h2 @ W3 (wave w = col-tile w, 16 cols), bf16 out ----
        f32x4 acc3 = {0.f, 0.f, 0.f, 0.f};
#pragma unroll
        for (int ks = 0; ks < 4; ++ks) {
            const float* rp = &rows[cl][ks * 32 + g * 4];
            float4 aL = *(const float4*)rp;
            float4 aH = *(const float4*)(rp + 16);
            short8v bh2, bl2;
#define SPLIT1(J, V)                                                        \
            {                                                               \
                unsigned u = __float_as_uint(V);                            \
                bh2[J] = (short)(u >> 16);                                  \
                float res = (V) - __uint_as_float(u & 0xFFFF0000u);         \
                bl2[J] = (short)(__float_as_uint(res) >> 16);               \
            }
            SPLIT1(0, aL.x) SPLIT1(1, aL.y) SPLIT1(2, aL.z) SPLIT1(3, aL.w)
            SPLIT1(4, aH.x) SPLIT1(5, aH.y) SPLIT1(6, aH.z) SPLIT1(7, aH.w)
#undef SPLIT1
            size_t fo = ((size_t)(wave * 4 + ks) * 64 + lane) * 8;
            short8v wh = *(const short8v*)(W3hF + fo);
            short8v wl = *(const short8v*)(W3lF + fo);
            acc3 = __builtin_amdgcn_mfma_f32_16x16x32_bf16(bh2, wh, acc3, 0, 0, 0);
            acc3 = __builtin_amdgcn_mfma_f32_16x16x32_bf16(bl2, wh, acc3, 0, 0, 0);
            acc3 = __builtin_amdgcn_mfma_f32_16x16x32_bf16(bh2, wl, acc3, 0, 0, 0);
        }
        int col3 = wave * 16 + cl;
#pragma unroll
        for (int r = 0; r < 4; ++r) {
            int gr = rowbase + g * 4 + r;
            if (gr < n) outB[(size_t)gr * 64 + col3] = f2bf(acc3[r]);
        }
    }
}

// ------- agg64: bf16 T gather (4 nodes/wave, uint2/lane), f32 out + bias -------

__global__ __launch_bounds__(256) void agg64_k(const unsigned short* __restrict__ tB,
                                               const int* __restrict__ offs,
                                               const int* __restrict__ esrc,
                                               const float* __restrict__ inv,
                                               const float* __restrict__ bias,
                                               float* __restrict__ out, int n) {
    int gt = blockIdx.x * 256 + threadIdx.x;
    int wv = gt >> 6;
    int q = (threadIdx.x >> 4) & 3;
    int l4 = threadIdx.x & 15;
    int node = wv * 4 + q;
    if (node >= n) return;
    int beg = offs[node], end = offs[node + 1];
    const uint2* __restrict__ t2 = (const uint2*)tB;  // 8B = 4 bf16; row = 16 uint2
    float ax = 0.f, ay = 0.f, az = 0.f, aw = 0.f;
    int j = beg;
#define ACC4(V)                                                             \
    {                                                                       \
        ax += __uint_as_float((V).x << 16);                                 \
        ay += __uint_as_float((V).x & 0xffff0000u);                         \
        az += __uint_as_float((V).y << 16);                                 \
        aw += __uint_as_float((V).y & 0xffff0000u);                         \
    }
    for (; j + 4 <= end; j += 4) {
        int s0 = esrc[j], s1 = esrc[j + 1], s2 = esrc[j + 2], s3 = esrc[j + 3];
        uint2 v0 = t2[(size_t)s0 * 16 + l4];
        uint2 v1 = t2[(size_t)s1 * 16 + l4];
        uint2 v2 = t2[(size_t)s2 * 16 + l4];
        uint2 v3 = t2[(size_t)s3 * 16 + l4];
        ACC4(v0) ACC4(v1) ACC4(v2) ACC4(v3)
    }
    for (; j < end; ++j) {
        uint2 v = t2[(size_t)esrc[j] * 16 + l4];
        ACC4(v)
    }
#undef ACC4
    float sc = inv[node];
    float4 b = ((const float4*)bias)[l4];
    float4 r;
    r.x = ax * sc + b.x; r.y = ay * sc + b.y;
    r.z = az * sc + b.z; r.w = aw * sc + b.w;
    ((float4*)out)[(size_t)node * 16 + l4] = r;
}

// ---------------- launch ----------------

extern "C" void kernel_launch(void* const* d_in, const int* in_sizes, int n_in,
                              void* d_out, int out_size, void* d_ws, size_t ws_size,
                              hipStream_t stream) {
    const int N = N_NODES, E = N_EDGES;
    const float* feat = (const float*)d_in[0];
    const int* src = (const int*)d_in[1];
    const int* dst = (const int*)d_in[2];
    const float* W1 = (const float*)d_in[3];
    const float* b1 = (const float*)d_in[4];
    const float* W2 = (const float*)d_in[5];
    const float* b2 = (const float*)d_in[6];
    const float* W3 = (const float*)d_in[7];
    const float* b3 = (const float*)d_in[8];
    float* out = (float*)d_out;

    const int nScanBlocks = (N + SCAN_CHUNK - 1) / SCAN_CHUNK;  // 49

    // workspace layout (int units from base)
    float* B0 = (float*)d_ws;                       // N*128 f32 region (T bf16 here)
    float* B1 = B0 + (size_t)N * 128;               // N*128 f32 region (h1 bf16 here)
    int* deg = (int*)(B1 + (size_t)N * 128);        // N
    float* invd = (float*)(deg + N);                // N
    int* offs = (int*)(invd + N);                   // N+2
    int* cursor = offs + N + 2;                     // N
    int* esrc = cursor + N;                         // E
    int* blockSums = esrc + E;                      // 64 (padded)
    uintptr_t p = (uintptr_t)(blockSums + 64);
    p = (p + 15) & ~(uintptr_t)15;
    unsigned short* featB = (unsigned short*)p;     // N*128 bf16 (12.8MB)
    short* W1h = (short*)(featB + (size_t)N * 128); // frag-major W bufs (160KB)
    short* W1l = W1h + 16384;
    short* W2h = W1l + 16384;
    short* W2l = W2h + 16384;
    short* W3h = W2l + 16384;
    short* W3l = W3h + 8192;

    unsigned short* h1B = (unsigned short*)B1;      // h1 bf16, N*128
    unsigned short* tB = (unsigned short*)B0;       // T bf16, N*64

    // --- CSR build + feat cvt ---
    hipMemsetAsync(deg, 0, (size_t)N * sizeof(int), stream);
    const int n8 = N * 128 / 8;  // 800000 convert threads
    count_cvt_k<<<(n8 + 255) / 256, 256, 0, stream>>>(dst, deg, feat, (uint4*)featB,
                                                      E, n8);
    scan_part_k<<<nScanBlocks, 256, 0, stream>>>(deg, blockSums, N);
    scan_final_k<<<nScanBlocks, 256, 0, stream>>>(deg, blockSums, offs, cursor, invd,
                                                  N, nScanBlocks, E);
    fill_prep_k<<<FILL_BLOCKS + 20, 256, 0, stream>>>(src, dst, cursor, esrc, E,
                                                      W1, W2, W3, W1h, W1l, W2h, W2l,
                                                      W3h, W3l);

    const int fusedGrid = (N + 15) / 16;     // 3125
    const int agg64Grid = (N + 15) / 16;

    // --- layer 1: fused agg+gemm (featB -> h1B bf16) ---
    fused_agg_gemm_k<false><<<fusedGrid, 256, 0, stream>>>(
        featB, offs, esrc, invd, W1h, W1l, b1, nullptr, nullptr, h1B, N);
    // --- layer 2 + 3a: fused agg+gemm+W3 (h1B -> T bf16) ---
    fused_agg_gemm_k<true><<<fusedGrid, 256, 0, stream>>>(
        h1B, offs, esrc, invd, W2h, W2l, b2, W3h, W3l, tB, N);
    // --- layer 3b: agg64(T) + b3 -> out (f32) ---
    agg64_k<<<agg64Grid, 256, 0, stream>>>(tB, offs, esrc, invd, b3, out, N);
}

// Round 16
// 239.913 us; speedup vs baseline: 1.9641x; 1.0161x over previous
//
#include <hip/hip_runtime.h>
#include <stdint.h>

// GCN: 3-layer GraphConv (norm='right'), N=50000, E=600000, 128->128->128->64.
//
// R1: hierarchical scan (110us -> ~5us).                        [442us]
// R4/R5: MFMA split-bf16 + fragment-major W + XCD swizzle.      [337us]
// R7/R8/R9: fused agg+gemm+W3tail, occupancy tuning.            [281us]
// R10: bf16 activations on all gathered tensors (rows 512->256B),
//     absmax 1.95e-3 (threshold 5.43e-3).                       [248us]
// R11: scan_blocks_k deleted + launch_bounds(256,8).            [243.8us]
// R13: cooperative-launch consolidation FAILED (hipLaunchCooperativeKernel
//     doesn't execute under the harness launch path -> garbage CSR).
// R14: REVERT to R11 (known-good). Gather path saturated (~3-3.4 TB/s,
//     occupancy-insensitive); bf16 is the precision floor for byte-cutting;
//     per-XCD blocking inapplicable (random graph). Practical roofline.
// R15: resubmit (GPU acquisition timeout, no data).

#define N_NODES 50000
#define N_EDGES 600000
#define SCAN_CHUNK 1024
#define FILL_BLOCKS ((N_EDGES + 255) / 256)   // 2344

typedef __attribute__((ext_vector_type(8))) short short8v;
typedef __attribute__((ext_vector_type(4))) float f32x4;

__device__ __forceinline__ unsigned short f2bf(float f) {  // RNE
    unsigned u = __float_as_uint(f);
    unsigned r = (u + 0x7fffu + ((u >> 16) & 1u)) >> 16;
    return (unsigned short)r;
}

// ---------------- CSR build ----------------

// count degrees + convert feat (fp32 -> bf16 packed), independent work
__global__ void count_cvt_k(const int* __restrict__ dst, int* __restrict__ deg,
                            const float* __restrict__ feat, uint4* __restrict__ featB,
                            int e, int n8) {
    int i = blockIdx.x * 256 + threadIdx.x;
    if (i < e) atomicAdd(&deg[dst[i]], 1);
    if (i < n8) {
        const float4* f4 = (const float4*)feat;
        float4 a = f4[(size_t)i * 2];
        float4 b = f4[(size_t)i * 2 + 1];
        uint4 o;
        o.x = (unsigned)f2bf(a.x) | ((unsigned)f2bf(a.y) << 16);
        o.y = (unsigned)f2bf(a.z) | ((unsigned)f2bf(a.w) << 16);
        o.z = (unsigned)f2bf(b.x) | ((unsigned)f2bf(b.y) << 16);
        o.w = (unsigned)f2bf(b.z) | ((unsigned)f2bf(b.w) << 16);
        featB[i] = o;
    }
}

__global__ __launch_bounds__(256) void scan_part_k(const int* __restrict__ deg,
                                                   int* __restrict__ blockSums, int n) {
    __shared__ int red[256];
    int t = threadIdx.x;
    int base = blockIdx.x * SCAN_CHUNK + t * 4;
    int s = 0;
#pragma unroll
    for (int k = 0; k < 4; ++k) {
        int i = base + k;
        if (i < n) s += deg[i];
    }
    red[t] = s;
    __syncthreads();
    for (int off = 128; off > 0; off >>= 1) {
        if (t < off) red[t] += red[t + off];
        __syncthreads();
    }
    if (t == 0) blockSums[blockIdx.x] = red[0];
}

// local scan; block prefix computed in-block from blockSums (<=64 entries);
// offs[N]=E written statically. Also emits cursor + inv_deg.
__global__ __launch_bounds__(256) void scan_final_k(const int* __restrict__ deg,
                                                    const int* __restrict__ blockSums,
                                                    int* __restrict__ offs,
                                                    int* __restrict__ cursor,
                                                    float* __restrict__ inv,
                                                    int n, int nb, int e) {
    __shared__ int red[256];
    __shared__ int bs[64];
    int t = threadIdx.x;
    if (t < 64) bs[t] = (t < nb && t < (int)blockIdx.x) ? blockSums[t] : 0;
    int base = blockIdx.x * SCAN_CHUNK + t * 4;
    int v[4];
    int s = 0;
#pragma unroll
    for (int k = 0; k < 4; ++k) {
        int i = base + k;
        v[k] = (i < n) ? deg[i] : 0;
        s += v[k];
    }
    red[t] = s;
    __syncthreads();
    int bpfx = 0;
#pragma unroll
    for (int i = 0; i < 64; ++i) bpfx += bs[i];
    for (int off = 1; off < 256; off <<= 1) {
        int x = (t >= off) ? red[t - off] : 0;
        __syncthreads();
        red[t] += x;
        __syncthreads();
    }
    int run = bpfx + red[t] - s;
#pragma unroll
    for (int k = 0; k < 4; ++k) {
        int i = base + k;
        if (i < n) {
            offs[i] = run;
            cursor[i] = run;
            inv[i] = 1.0f / (float)(v[k] > 0 ? v[k] : 1);
            run += v[k];
        }
    }
    if (blockIdx.x == 0 && t == 0) offs[n] = e;
}

// ---- weight prep helper: W[K][NC] fp32 -> fragment-major split-bf16 hi/lo ----
// Frag idx: tile T (NC/16), kstep ks (4), lane l (64): 8 bf16 at (((T*4+ks)*64)+l)*8.
// Lane l=g*16+cl holds W[k][T*16+cl], k=ks*32+g*4+(j&3)+16*(j>>2).

__device__ __forceinline__ void prep_one(const float* __restrict__ W, short* hiF,
                                         short* loF, int NC, int idx) {
    int lane = idx & 63;
    int ks = (idx >> 6) & 3;
    int T = idx >> 8;
    int g = lane >> 4, cl = lane & 15;
    int col = T * 16 + cl;
    short8v h, l;
#pragma unroll
    for (int j = 0; j < 8; ++j) {
        int k = ks * 32 + g * 4 + (j & 3) + ((j >> 2) << 4);
        float w = W[(size_t)k * NC + col];
        unsigned u = __float_as_uint(w);
        h[j] = (short)(u >> 16);
        float res = w - __uint_as_float(u & 0xFFFF0000u);
        l[j] = (short)(__float_as_uint(res) >> 16);
    }
    ((short8v*)hiF)[idx] = h;
    ((short8v*)loF)[idx] = l;
}

// fill CSR (blocks < FILL_BLOCKS) + weight prep (blocks >= FILL_BLOCKS)
__global__ void fill_prep_k(const int* __restrict__ src, const int* __restrict__ dst,
                            int* __restrict__ cursor, int* __restrict__ esrc, int e,
                            const float* __restrict__ W1, const float* __restrict__ W2,
                            const float* __restrict__ W3,
                            short* W1h, short* W1l, short* W2h, short* W2l,
                            short* W3h, short* W3l) {
    int b = blockIdx.x;
    if (b < FILL_BLOCKS) {
        int i = b * 256 + threadIdx.x;
        if (i < e) {
            int p = atomicAdd(&cursor[dst[i]], 1);
            esrc[p] = src[i];
        }
    } else {
        int idx = (b - FILL_BLOCKS) * 256 + threadIdx.x;
        if (idx < 2048) prep_one(W1, W1h, W1l, 128, idx);
        else if (idx < 4096) prep_one(W2, W2h, W2l, 128, idx - 2048);
        else if (idx < 5120) prep_one(W3, W3h, W3l, 64, idx - 4096);
    }
}

// ---------------- fused agg(bf16 gather) + gemm (+ optional W3 tail) ----------
// Block = 256 thr = 4 waves = 16 dst rows. Gather rows are bf16 (256B):
// 32 lanes x uint2 (4 bf16 each), unpack via shift/and, accumulate f32.
// Phase 2: split-bf16 MFMA vs frag-major W; outputs stored bf16.

template <bool W3TAIL>
__global__ __launch_bounds__(256, 8) void fused_agg_gemm_k(
    const unsigned short* __restrict__ hB, const int* __restrict__ offs,
    const int* __restrict__ esrc, const float* __restrict__ inv,
    const short* __restrict__ WhF, const short* __restrict__ WlF,
    const float* __restrict__ bias,
    const short* __restrict__ W3hF, const short* __restrict__ W3lF,
    unsigned short* __restrict__ outB, int n) {
    __shared__ float rows[16][132];  // +4 pad
    int wave = threadIdx.x >> 6;
    int lane = threadIdx.x & 63;
    int rowbase = blockIdx.x * 16;

    // ---- phase 1: aggregate 4 rows per wave (bf16 gather) ----
    {
        int half = lane >> 5;
        int l5 = lane & 31;
        const uint2* __restrict__ h2 = (const uint2*)hB;  // 8B = 4 bf16
#pragma unroll
        for (int it = 0; it < 2; ++it) {
            int r = wave * 4 + it * 2 + half;
            int node = rowbase + r;
            float ax = 0.f, ay = 0.f, az = 0.f, aw = 0.f;
            if (node < n) {
                int beg = offs[node], end = offs[node + 1];
                int j = beg;
#define ACC4(V)                                                             \
                {                                                           \
                    ax += __uint_as_float((V).x << 16);                     \
                    ay += __uint_as_float((V).x & 0xffff0000u);             \
                    az += __uint_as_float((V).y << 16);                     \
                    aw += __uint_as_float((V).y & 0xffff0000u);             \
                }
                for (; j + 4 <= end; j += 4) {
                    int s0 = esrc[j], s1 = esrc[j + 1];
                    int s2 = esrc[j + 2], s3 = esrc[j + 3];
                    uint2 v0 = h2[(size_t)s0 * 32 + l5];
                    uint2 v1 = h2[(size_t)s1 * 32 + l5];
                    uint2 v2 = h2[(size_t)s2 * 32 + l5];
                    uint2 v3 = h2[(size_t)s3 * 32 + l5];
                    ACC4(v0) ACC4(v1) ACC4(v2) ACC4(v3)
                }
                for (; j < end; ++j) {
                    uint2 v = h2[(size_t)esrc[j] * 32 + l5];
                    ACC4(v)
                }
#undef ACC4
                float sc = inv[node];
                ax *= sc; ay *= sc; az *= sc; aw *= sc;
            }
            float4 r4; r4.x = ax; r4.y = ay; r4.z = az; r4.w = aw;
            *(float4*)&rows[r][l5 * 4] = r4;
        }
    }
    __syncthreads();

    // ---- phase 2: MFMA, wave w = cols w*32..+32, rows 0..15 ----
    int g = lane >> 4, cl = lane & 15;
    short8v ah[4], al[4];
#pragma unroll
    for (int ks = 0; ks < 4; ++ks) {
        const float* rp = &rows[cl][ks * 32 + g * 4];
        float4 aL = *(const float4*)rp;
        float4 aH = *(const float4*)(rp + 16);
#define SPLIT1(J, V)                                                        \
        {                                                                   \
            unsigned u = __float_as_uint(V);                                \
            ah[ks][J] = (short)(u >> 16);                                   \
            float res = (V) - __uint_as_float(u & 0xFFFF0000u);             \
            al[ks][J] = (short)(__float_as_uint(res) >> 16);                \
        }
        SPLIT1(0, aL.x) SPLIT1(1, aL.y) SPLIT1(2, aL.z) SPLIT1(3, aL.w)
        SPLIT1(4, aH.x) SPLIT1(5, aH.y) SPLIT1(6, aH.z) SPLIT1(7, aH.w)
#undef SPLIT1
    }
    if (W3TAIL) __syncthreads();  // A-frag reads done before h2 overwrites LDS

    f32x4 acc[2];
    acc[0] = (f32x4){0.f, 0.f, 0.f, 0.f};
    acc[1] = (f32x4){0.f, 0.f, 0.f, 0.f};
#pragma unroll
    for (int ks = 0; ks < 4; ++ks) {
#pragma unroll
        for (int t = 0; t < 2; ++t) {
            int tileIdx = wave * 2 + t;
            size_t fo = ((size_t)(tileIdx * 4 + ks) * 64 + lane) * 8;
            short8v bh = *(const short8v*)(WhF + fo);
            short8v bl = *(const short8v*)(WlF + fo);
            acc[t] = __builtin_amdgcn_mfma_f32_16x16x32_bf16(ah[ks], bh, acc[t], 0, 0, 0);
            acc[t] = __builtin_amdgcn_mfma_f32_16x16x32_bf16(al[ks], bh, acc[t], 0, 0, 0);
            acc[t] = __builtin_amdgcn_mfma_f32_16x16x32_bf16(ah[ks], bl, acc[t], 0, 0, 0);
        }
    }

#pragma unroll
    for (int t = 0; t < 2; ++t) {
        int col = (wave * 2 + t) * 16 + cl;
        float bv = bias[col];
#pragma unroll
        for (int r = 0; r < 4; ++r) {
            float v = fmaxf(acc[t][r] + bv, 0.f);
            if (!W3TAIL) {
                int gr = rowbase + g * 4 + r;
                if (gr < n) outB[(size_t)gr * 128 + col] = f2bf(v);
            } else {
                rows[g * 4 + r][col] = v;  // h2 back into LDS (f32)
            }
        }
    }

    if (W3TAIL) {
        __syncthreads();
        // ---- phase 3: T = h2 @ W3 (wave w = col-tile w, 16 cols), bf16 out ----
        f32x4 acc3 = {0.f, 0.f, 0.f, 0.f};
#pragma unroll
        for (int ks = 0; ks < 4; ++ks) {
            const float* rp = &rows[cl][ks * 32 + g * 4];
            float4 aL = *(const float4*)rp;
            float4 aH = *(const float4*)(rp + 16);
            short8v bh2, bl2;
#define SPLIT1(J, V)                                                        \
            {                                                               \
                unsigned u = __float_as_uint(V);                            \
                bh2[J] = (short)(u >> 16);                                  \
                float res = (V) - __uint_as_float(u & 0xFFFF0000u);         \
                bl2[J] = (short)(__float_as_uint(res) >> 16);               \
            }
            SPLIT1(0, aL.x) SPLIT1(1, aL.y) SPLIT1(2, aL.z) SPLIT1(3, aL.w)
            SPLIT1(4, aH.x) SPLIT1(5, aH.y) SPLIT1(6, aH.z) SPLIT1(7, aH.w)
#undef SPLIT1
            size_t fo = ((size_t)(wave * 4 + ks) * 64 + lane) * 8;
            short8v wh = *(const short8v*)(W3hF + fo);
            short8v wl = *(const short8v*)(W3lF + fo);
            acc3 = __builtin_amdgcn_mfma_f32_16x16x32_bf16(bh2, wh, acc3, 0, 0, 0);
            acc3 = __builtin_amdgcn_mfma_f32_16x16x32_bf16(bl2, wh, acc3, 0, 0, 0);
            acc3 = __builtin_amdgcn_mfma_f32_16x16x32_bf16(bh2, wl, acc3, 0, 0, 0);
        }
        int col3 = wave * 16 + cl;
#pragma unroll
        for (int r = 0; r < 4; ++r) {
            int gr = rowbase + g * 4 + r;
            if (gr < n) outB[(size_t)gr * 64 + col3] = f2bf(acc3[r]);
        }
    }
}

// ------- agg64: bf16 T gather (4 nodes/wave, uint2/lane), f32 out + bias -------

__global__ __launch_bounds__(256) void agg64_k(const unsigned short* __restrict__ tB,
                                               const int* __restrict__ offs,
                                               const int* __restrict__ esrc,
                                               const float* __restrict__ inv,
                                               const float* __restrict__ bias,
                                               float* __restrict__ out, int n) {
    int gt = blockIdx.x * 256 + threadIdx.x;
    int wv = gt >> 6;
    int q = (threadIdx.x >> 4) & 3;
    int l4 = threadIdx.x & 15;
    int node = wv * 4 + q;
    if (node >= n) return;
    int beg = offs[node], end = offs[node + 1];
    const uint2* __restrict__ t2 = (const uint2*)tB;  // 8B = 4 bf16; row = 16 uint2
    float ax = 0.f, ay = 0.f, az = 0.f, aw = 0.f;
    int j = beg;
#define ACC4(V)                                                             \
    {                                                                       \
        ax += __uint_as_float((V).x << 16);                                 \
        ay += __uint_as_float((V).x & 0xffff0000u);                         \
        az += __uint_as_float((V).y << 16);                                 \
        aw += __uint_as_float((V).y & 0xffff0000u);                         \
    }
    for (; j + 4 <= end; j += 4) {
        int s0 = esrc[j], s1 = esrc[j + 1], s2 = esrc[j + 2], s3 = esrc[j + 3];
        uint2 v0 = t2[(size_t)s0 * 16 + l4];
        uint2 v1 = t2[(size_t)s1 * 16 + l4];
        uint2 v2 = t2[(size_t)s2 * 16 + l4];
        uint2 v3 = t2[(size_t)s3 * 16 + l4];
        ACC4(v0) ACC4(v1) ACC4(v2) ACC4(v3)
    }
    for (; j < end; ++j) {
        uint2 v = t2[(size_t)esrc[j] * 16 + l4];
        ACC4(v)
    }
#undef ACC4
    float sc = inv[node];
    float4 b = ((const float4*)bias)[l4];
    float4 r;
    r.x = ax * sc + b.x; r.y = ay * sc + b.y;
    r.z = az * sc + b.z; r.w = aw * sc + b.w;
    ((float4*)out)[(size_t)node * 16 + l4] = r;
}

// ---------------- launch ----------------

extern "C" void kernel_launch(void* const* d_in, const int* in_sizes, int n_in,
                              void* d_out, int out_size, void* d_ws, size_t ws_size,
                              hipStream_t stream) {
    const int N = N_NODES, E = N_EDGES;
    const float* feat = (const float*)d_in[0];
    const int* src = (const int*)d_in[1];
    const int* dst = (const int*)d_in[2];
    const float* W1 = (const float*)d_in[3];
    const float* b1 = (const float*)d_in[4];
    const float* W2 = (const float*)d_in[5];
    const float* b2 = (const float*)d_in[6];
    const float* W3 = (const float*)d_in[7];
    const float* b3 = (const float*)d_in[8];
    float* out = (float*)d_out;

    const int nScanBlocks = (N + SCAN_CHUNK - 1) / SCAN_CHUNK;  // 49

    // workspace layout (int units from base)
    float* B0 = (float*)d_ws;                       // N*128 f32 region (T bf16 here)
    float* B1 = B0 + (size_t)N * 128;               // N*128 f32 region (h1 bf16 here)
    int* deg = (int*)(B1 + (size_t)N * 128);        // N
    float* invd = (float*)(deg + N);                // N
    int* offs = (int*)(invd + N);                   // N+2
    int* cursor = offs + N + 2;                     // N
    int* esrc = cursor + N;                         // E
    int* blockSums = esrc + E;                      // 64 (padded)
    uintptr_t p = (uintptr_t)(blockSums + 64);
    p = (p + 15) & ~(uintptr_t)15;
    unsigned short* featB = (unsigned short*)p;     // N*128 bf16 (12.8MB)
    short* W1h = (short*)(featB + (size_t)N * 128); // frag-major W bufs (160KB)
    short* W1l = W1h + 16384;
    short* W2h = W1l + 16384;
    short* W2l = W2h + 16384;
    short* W3h = W2l + 16384;
    short* W3l = W3h + 8192;

    unsigned short* h1B = (unsigned short*)B1;      // h1 bf16, N*128
    unsigned short* tB = (unsigned short*)B0;       // T bf16, N*64

    // --- CSR build + feat cvt ---
    hipMemsetAsync(deg, 0, (size_t)N * sizeof(int), stream);
    const int n8 = N * 128 / 8;  // 800000 convert threads
    count_cvt_k<<<(n8 + 255) / 256, 256, 0, stream>>>(dst, deg, feat, (uint4*)featB,
                                                      E, n8);
    scan_part_k<<<nScanBlocks, 256, 0, stream>>>(deg, blockSums, N);
    scan_final_k<<<nScanBlocks, 256, 0, stream>>>(deg, blockSums, offs, cursor, invd,
                                                  N, nScanBlocks, E);
    fill_prep_k<<<FILL_BLOCKS + 20, 256, 0, stream>>>(src, dst, cursor, esrc, E,
                                                      W1, W2, W3, W1h, W1l, W2h, W2l,
                                                      W3h, W3l);

    const int fusedGrid = (N + 15) / 16;     // 3125
    const int agg64Grid = (N + 15) / 16;

    // --- layer 1: fused agg+gemm (featB -> h1B bf16) ---
    fused_agg_gemm_k<false><<<fusedGrid, 256, 0, stream>>>(
        featB, offs, esrc, invd, W1h, W1l, b1, nullptr, nullptr, h1B, N);
    // --- layer 2 + 3a: fused agg+gemm+W3 (h1B -> T bf16) ---
    fused_agg_gemm_k<true><<<fusedGrid, 256, 0, stream>>>(
        h1B, offs, esrc, invd, W2h, W2l, b2, W3h, W3l, tB, N);
    // --- layer 3b: agg64(T) + b3 -> out (f32) ---
    agg64_k<<<agg64Grid, 256, 0, stream>>>(tB, offs, esrc, invd, b3, out, N);
}